// Round 3
// baseline (6624.871 us; speedup 1.0000x reference)
//
#include <hip/hip_runtime.h>
#include <math.h>

#define EMB 256
#define HID 512
#define KTOP 5
#define NLIB 16384
#define NB 224
#define P_TOT 32768

#define BM 64
#define BN 128
#define BK 64
#define NTILE (NLIB / BN)   /* 128 */
#define NCHUNK (NTILE * 4)  /* 512 */

/* d_out float layout: [P] dominant | [P][7] abundances | [P][224] recon | [P][5] cand_sims */
#define OUT_DOM ((size_t)0)
#define OUT_AB  ((size_t)P_TOT)
#define OUT_RE  ((size_t)8 * P_TOT)
#define OUT_CS  ((size_t)232 * P_TOT)

/* ws byte layout */
#define WS_SCORES 0                              /* P*5 double */
#define WS_INVL   (P_TOT * KTOP * 8)             /* NLIB float */
#define WS_IDS8   (WS_INVL + NLIB * 4)           /* P*8 int */
#define WS_CIDS   (WS_IDS8 + P_TOT * 8 * 4)      /* P*5 int */

__device__ __forceinline__ bool better_(float v, int vi, float e, int ei) {
  return (v > e) || ((v == e) && (vi < ei));  /* jax top_k tie-break: lower id first */
}
__device__ __forceinline__ bool betterd_(double v, int vi, double e, int ei) {
  return (v > e) || ((v == e) && (vi < ei));
}

__device__ __forceinline__ void ins5_(float& s0, int& d0, float& s1, int& d1,
                                      float& s2, int& d2, float& s3, int& d3,
                                      float& s4, int& d4, float v, int vi) {
  if (!better_(v, vi, s4, d4)) return;
  s4 = v; d4 = vi;
  if (better_(s4, d4, s3, d3)) {
    float tf = s3; int td = d3; s3 = s4; d3 = d4; s4 = tf; d4 = td;
    if (better_(s3, d3, s2, d2)) {
      tf = s2; td = d2; s2 = s3; d2 = d3; s3 = tf; d3 = td;
      if (better_(s2, d2, s1, d1)) {
        tf = s1; td = d1; s1 = s2; d1 = d2; s2 = tf; d2 = td;
        if (better_(s1, d1, s0, d0)) {
          tf = s0; td = d0; s0 = s1; d0 = d1; s1 = tf; d1 = td;
        }
      }
    }
  }
}

__device__ __forceinline__ void ins8_(float m[8], int n[8], float v, int vi) {
  if (!better_(v, vi, m[7], n[7])) return;
  m[7] = v; n[7] = vi;
  #pragma unroll
  for (int q = 7; q >= 1; --q) {
    if (better_(m[q], n[q], m[q - 1], n[q - 1])) {
      float tf = m[q - 1]; m[q - 1] = m[q]; m[q] = tf;
      int td = n[q - 1]; n[q - 1] = n[q]; n[q] = td;
    }
  }
}

/* ---------------- kernel 1: library row inverse norms (f32 fast path) ---------------- */
__global__ __launch_bounds__(64) void libnorm_kernel(const float* __restrict__ lab,
                                                     float* __restrict__ invl) {
  const int row = blockIdx.x;
  const int lane = threadIdx.x;
  float4 v = *(const float4*)(lab + (size_t)row * EMB + lane * 4);
  float s = v.x * v.x + v.y * v.y + v.z * v.z + v.w * v.w;
  #pragma unroll
  for (int off = 32; off >= 1; off >>= 1) s += __shfl_down(s, off);
  if (lane == 0) invl[row] = 1.0f / (sqrtf(s) + 1e-12f);
}

/* ------------- kernel 2: score MLP (256->512->5), f64 accumulation ------------- */
__global__ __launch_bounds__(256) void score_mlp_kernel(
    const float* __restrict__ feat, const float* __restrict__ w1,
    const float* __restrict__ b1, const float* __restrict__ w2,
    const float* __restrict__ b2, double* __restrict__ scores) {
  __shared__ __align__(16) float xs[16 * 264];
  __shared__ __align__(16) float hs[16 * 516];
  const int t = threadIdx.x;
  const int pb = blockIdx.x * 16;

  #pragma unroll
  for (int i = 0; i < 4; ++i) {
    int F = i * 256 + t;
    int p = F >> 6, q = (F & 63) * 4;
    *(float4*)&xs[p * 264 + q] = *(const float4*)(feat + (size_t)(pb + p) * EMB + q);
  }
  __syncthreads();

  const int h0 = t, h1 = t + 256;
  double a0[16], a1[16];
  #pragma unroll
  for (int p = 0; p < 16; ++p) { a0[p] = 0.0; a1[p] = 0.0; }

  for (int i4 = 0; i4 < 64; ++i4) {
    const int i = i4 * 4;
    double w00 = w1[(i + 0) * HID + h0], w01 = w1[(i + 1) * HID + h0];
    double w02 = w1[(i + 2) * HID + h0], w03 = w1[(i + 3) * HID + h0];
    double w10 = w1[(i + 0) * HID + h1], w11 = w1[(i + 1) * HID + h1];
    double w12 = w1[(i + 2) * HID + h1], w13 = w1[(i + 3) * HID + h1];
    #pragma unroll
    for (int p = 0; p < 16; ++p) {
      float4 x = *(const float4*)&xs[p * 264 + i];
      a0[p] = fma((double)x.x, w00, a0[p]); a0[p] = fma((double)x.y, w01, a0[p]);
      a0[p] = fma((double)x.z, w02, a0[p]); a0[p] = fma((double)x.w, w03, a0[p]);
      a1[p] = fma((double)x.x, w10, a1[p]); a1[p] = fma((double)x.y, w11, a1[p]);
      a1[p] = fma((double)x.z, w12, a1[p]); a1[p] = fma((double)x.w, w13, a1[p]);
    }
  }
  const double bb0 = b1[h0], bb1 = b1[h1];
  #pragma unroll
  for (int p = 0; p < 16; ++p) {
    hs[p * 516 + h0] = (float)fmax(a0[p] + bb0, 0.0);
    hs[p * 516 + h1] = (float)fmax(a1[p] + bb1, 0.0);
  }
  __syncthreads();

  if (t < 80) {
    const int p = t / 5, o = t % 5;
    double acc = (double)b2[o];
    for (int h4 = 0; h4 < 128; ++h4) {
      float4 hv = *(const float4*)&hs[p * 516 + h4 * 4];
      acc = fma((double)hv.x, (double)w2[(h4 * 4 + 0) * 5 + o], acc);
      acc = fma((double)hv.y, (double)w2[(h4 * 4 + 1) * 5 + o], acc);
      acc = fma((double)hv.z, (double)w2[(h4 * 4 + 2) * 5 + o], acc);
      acc = fma((double)hv.w, (double)w2[(h4 * 4 + 3) * 5 + o], acc);
    }
    scores[(size_t)(pb + p) * 5 + o] = acc;
  }
}

/* ------------- kernel 3: fused sims GEMM (f32) + per-pixel top-8 candidate ids ------------- */
__global__ __launch_bounds__(512, 1) void sims_topk_kernel(
    const float* __restrict__ feat, const float* __restrict__ lab,
    const float* __restrict__ invl, int* __restrict__ ids8) {
  extern __shared__ float smem[];
  float* af = smem;               /* [64][256] */
  float* bl = smem + BM * EMB;    /* [2][128][64], f4-slot XOR-swizzled */
  const int t = threadIdx.x;
  const int tx = t & 31, ty = t >> 5;
  const int pb = blockIdx.x * BM;

  #pragma unroll
  for (int i = 0; i < 8; ++i) {
    int F = i * 512 + t;
    int p = F >> 6, q = (F & 63) * 4;
    *(float4*)(af + p * EMB + q) = *(const float4*)(feat + (size_t)(pb + p) * EMB + q);
  }

  int soff[4], ldw[4];
  #pragma unroll
  for (int i = 0; i < 4; ++i) {
    int F = i * 512 + t;
    int l = F >> 4, q = F & 15;
    int s = (l >> 2) & 15;
    soff[i] = l * EMB + 4 * (q ^ s);
    ldw[i] = l * BK + 4 * q;
  }
  #pragma unroll
  for (int i = 0; i < 4; ++i)
    *(float4*)(bl + ldw[i]) = *(const float4*)(lab + soff[i]);

  float acc[4][4];
  #pragma unroll
  for (int pp = 0; pp < 4; ++pp)
    #pragma unroll
    for (int jj = 0; jj < 4; ++jj) acc[pp][jj] = 0.f;

  float ts[4][5]; int ti[4][5];
  #pragma unroll
  for (int pp = 0; pp < 4; ++pp)
    #pragma unroll
    for (int k = 0; k < 5; ++k) { ts[pp][k] = -3.0e38f; ti[pp][k] = 0x7fffffff; }

  for (int c = 0; c < NCHUNK; ++c) {
    const int tile = c >> 2, kc = c & 3;
    const int c1 = c + 1;
    float4 rB[4];
    if (c1 < NCHUNK) {
      const float* src = lab + (size_t)(c1 >> 2) * BN * EMB + (c1 & 3) * BK;
      #pragma unroll
      for (int i = 0; i < 4; ++i) rB[i] = *(const float4*)(src + soff[i]);
    }
    __syncthreads();

    const float* bb = bl + (c & 1) * (BN * BK);
    const float* arow = af + (ty * 4) * EMB + kc * BK;
    const float* brow = bb + (tx * 4) * BK;
    #pragma unroll
    for (int k4 = 0; k4 < 16; ++k4) {
      float4 av[4], bv[4];
      #pragma unroll
      for (int pp = 0; pp < 4; ++pp)
        av[pp] = *(const float4*)(arow + pp * EMB + k4 * 4);
      const int slot = ((k4 ^ (tx & 15))) * 4;
      #pragma unroll
      for (int jj = 0; jj < 4; ++jj)
        bv[jj] = *(const float4*)(brow + jj * BK + slot);
      #pragma unroll
      for (int pp = 0; pp < 4; ++pp)
        #pragma unroll
        for (int jj = 0; jj < 4; ++jj) {
          acc[pp][jj] = fmaf(av[pp].x, bv[jj].x, acc[pp][jj]);
          acc[pp][jj] = fmaf(av[pp].y, bv[jj].y, acc[pp][jj]);
          acc[pp][jj] = fmaf(av[pp].z, bv[jj].z, acc[pp][jj]);
          acc[pp][jj] = fmaf(av[pp].w, bv[jj].w, acc[pp][jj]);
        }
    }

    if (kc == 3) {
      float4 il = *(const float4*)(invl + tile * BN + tx * 4);
      const int idb = tile * BN + tx * 4;
      #pragma unroll
      for (int pp = 0; pp < 4; ++pp) {
        ins5_(ts[pp][0], ti[pp][0], ts[pp][1], ti[pp][1], ts[pp][2], ti[pp][2],
              ts[pp][3], ti[pp][3], ts[pp][4], ti[pp][4], acc[pp][0] * il.x, idb + 0);
        ins5_(ts[pp][0], ti[pp][0], ts[pp][1], ti[pp][1], ts[pp][2], ti[pp][2],
              ts[pp][3], ti[pp][3], ts[pp][4], ti[pp][4], acc[pp][1] * il.y, idb + 1);
        ins5_(ts[pp][0], ti[pp][0], ts[pp][1], ti[pp][1], ts[pp][2], ti[pp][2],
              ts[pp][3], ti[pp][3], ts[pp][4], ti[pp][4], acc[pp][2] * il.z, idb + 2);
        ins5_(ts[pp][0], ti[pp][0], ts[pp][1], ti[pp][1], ts[pp][2], ti[pp][2],
              ts[pp][3], ti[pp][3], ts[pp][4], ti[pp][4], acc[pp][3] * il.w, idb + 3);
        acc[pp][0] = 0.f; acc[pp][1] = 0.f; acc[pp][2] = 0.f; acc[pp][3] = 0.f;
      }
    }

    if (c1 < NCHUNK) {
      float* dst = bl + (c1 & 1) * (BN * BK);
      #pragma unroll
      for (int i = 0; i < 4; ++i) *(float4*)(dst + ldw[i]) = rB[i];
    }
  }

  __syncthreads();
  /* overlay: [64][161] sims + [64][161] ids */
  float* simsL = smem;
  int* idsL = (int*)(smem + 64 * 161);
  #pragma unroll
  for (int pp = 0; pp < 4; ++pp) {
    const int p = ty * 4 + pp;
    #pragma unroll
    for (int k = 0; k < 5; ++k) {
      simsL[p * 161 + tx * 5 + k] = ts[pp][k];
      idsL[p * 161 + tx * 5 + k] = ti[pp][k];
    }
  }
  __syncthreads();

  if (t < 64) {
    float m[8]; int n[8];
    #pragma unroll
    for (int j = 0; j < 8; ++j) { m[j] = -3.0e38f; n[j] = 0x7fffffff; }
    for (int c = 0; c < 160; ++c)
      ins8_(m, n, simsL[t * 161 + c], idsL[t * 161 + c]);
    const int gp = pb + t;
    #pragma unroll
    for (int j = 0; j < 8; ++j) ids8[(size_t)gp * 8 + j] = n[j];
  }
}

/* ------------- kernel 3b: exact f64 refinement of the 8 candidates ------------- */
__global__ __launch_bounds__(256) void refine_kernel(
    const float* __restrict__ feat, const float* __restrict__ lab,
    const int* __restrict__ ids8, float* __restrict__ out,
    int* __restrict__ cids) {
  const int t = threadIdx.x;
  const int lane = t & 63;
  const int p = blockIdx.x * 4 + (t >> 6);

  float4 f = *(const float4*)(feat + (size_t)p * EMB + lane * 4);
  const double fx = f.x, fy = f.y, fz = f.z, fw = f.w;
  double sf = fx * fx + fy * fy + fz * fz + fw * fw;

  int id[8];
  #pragma unroll
  for (int j = 0; j < 8; ++j) id[j] = ids8[(size_t)p * 8 + j];

  double dot[8], sl[8];
  #pragma unroll
  for (int j = 0; j < 8; ++j) {
    float4 l = *(const float4*)(lab + (size_t)id[j] * EMB + lane * 4);
    const double lx = l.x, ly = l.y, lz = l.z, lw = l.w;
    dot[j] = fma(fx, lx, fma(fy, ly, fma(fz, lz, fw * lw)));
    sl[j]  = fma(lx, lx, fma(ly, ly, fma(lz, lz, lw * lw)));
  }
  #pragma unroll
  for (int off = 32; off >= 1; off >>= 1) {
    sf += __shfl_xor(sf, off);
    #pragma unroll
    for (int j = 0; j < 8; ++j) {
      dot[j] += __shfl_xor(dot[j], off);
      sl[j]  += __shfl_xor(sl[j], off);
    }
  }
  if (lane == 0) {
    const double invf = 1.0 / (sqrt(sf) + 1e-12);
    double s[8];
    #pragma unroll
    for (int j = 0; j < 8; ++j)
      s[j] = dot[j] * (1.0 / (sqrt(sl[j]) + 1e-12)) * invf;
    /* bubble network: desc by value, ties by lower id */
    #pragma unroll
    for (int pass = 0; pass < 7; ++pass) {
      #pragma unroll
      for (int i = 0; i < 7; ++i) {
        if (i < 7 - pass) {
          if (betterd_(s[i + 1], id[i + 1], s[i], id[i])) {
            double tv = s[i]; s[i] = s[i + 1]; s[i + 1] = tv;
            int td = id[i]; id[i] = id[i + 1]; id[i + 1] = td;
          }
        }
      }
    }
    #pragma unroll
    for (int k = 0; k < 5; ++k) {
      out[OUT_CS + (size_t)p * 5 + k] = (float)s[k];
      cids[(size_t)p * 5 + k] = id[k];
    }
  }
}

/* ------------- kernel 4: abundance MLP (f64) + softmax + recon + dominant ------------- */
__global__ __launch_bounds__(256) void abund_kernel(
    const float* __restrict__ feat, const double* __restrict__ scores,
    const float* __restrict__ w1, const float* __restrict__ b1,
    const float* __restrict__ w2, const float* __restrict__ b2,
    const float* __restrict__ proto, const int* __restrict__ cids,
    float* __restrict__ out) {
  __shared__ __align__(16) float xs[16 * 264];
  __shared__ __align__(16) float hs[16 * 520];
  __shared__ double scs[16 * 5];
  __shared__ double lo[16 * 8];
  __shared__ double sAB[16 * 8];
  __shared__ int ids_s[16 * 5];
  const int t = threadIdx.x;
  const int pb = blockIdx.x * 16;

  #pragma unroll
  for (int i = 0; i < 4; ++i) {
    int F = i * 256 + t;
    int p = F >> 6, q = (F & 63) * 4;
    *(float4*)&xs[p * 264 + q] = *(const float4*)(feat + (size_t)(pb + p) * EMB + q);
  }
  if (t < 80) scs[t] = scores[(size_t)(pb + t / 5) * 5 + (t % 5)];
  __syncthreads();

  const int h0 = t, h1 = t + 256;
  double a0[16], a1[16];
  #pragma unroll
  for (int p = 0; p < 16; ++p) { a0[p] = 0.0; a1[p] = 0.0; }

  for (int i4 = 0; i4 < 64; ++i4) {   /* dims 0..255 */
    const int i = i4 * 4;
    double w00 = w1[(i + 0) * HID + h0], w01 = w1[(i + 1) * HID + h0];
    double w02 = w1[(i + 2) * HID + h0], w03 = w1[(i + 3) * HID + h0];
    double w10 = w1[(i + 0) * HID + h1], w11 = w1[(i + 1) * HID + h1];
    double w12 = w1[(i + 2) * HID + h1], w13 = w1[(i + 3) * HID + h1];
    #pragma unroll
    for (int p = 0; p < 16; ++p) {
      float4 x = *(const float4*)&xs[p * 264 + i];
      a0[p] = fma((double)x.x, w00, a0[p]); a0[p] = fma((double)x.y, w01, a0[p]);
      a0[p] = fma((double)x.z, w02, a0[p]); a0[p] = fma((double)x.w, w03, a0[p]);
      a1[p] = fma((double)x.x, w10, a1[p]); a1[p] = fma((double)x.y, w11, a1[p]);
      a1[p] = fma((double)x.z, w12, a1[p]); a1[p] = fma((double)x.w, w13, a1[p]);
    }
  }
  #pragma unroll
  for (int r = 0; r < 5; ++r) {       /* dims 256..260: f64 scores */
    double wA = w1[(256 + r) * HID + h0], wB = w1[(256 + r) * HID + h1];
    #pragma unroll
    for (int p = 0; p < 16; ++p) {
      double x = scs[p * 5 + r];
      a0[p] = fma(x, wA, a0[p]);
      a1[p] = fma(x, wB, a1[p]);
    }
  }
  const double bb0 = b1[h0], bb1 = b1[h1];
  #pragma unroll
  for (int p = 0; p < 16; ++p) {
    hs[p * 520 + h0] = (float)fmax(a0[p] + bb0, 0.0);
    hs[p * 520 + h1] = (float)fmax(a1[p] + bb1, 0.0);
  }
  __syncthreads();

  if (t < 112) {
    const int p = t / 7, o = t % 7;
    double acc = (double)b2[o];
    for (int h4 = 0; h4 < 128; ++h4) {
      float4 hv = *(const float4*)&hs[p * 520 + h4 * 4];
      acc = fma((double)hv.x, (double)w2[(h4 * 4 + 0) * 7 + o], acc);
      acc = fma((double)hv.y, (double)w2[(h4 * 4 + 1) * 7 + o], acc);
      acc = fma((double)hv.z, (double)w2[(h4 * 4 + 2) * 7 + o], acc);
      acc = fma((double)hv.w, (double)w2[(h4 * 4 + 3) * 7 + o], acc);
    }
    lo[p * 8 + o] = acc;
  }
  __syncthreads();

  if (t < 16) {
    const int p = t, gp = pb + t;
    double m = lo[p * 8 + 0];
    #pragma unroll
    for (int o = 1; o < 7; ++o) m = fmax(m, lo[p * 8 + o]);
    double e[7]; double ssum = 0.0;
    #pragma unroll
    for (int o = 0; o < 7; ++o) { e[o] = exp(lo[p * 8 + o] - m); ssum += e[o]; }
    const double inv = 1.0 / ssum;
    #pragma unroll
    for (int o = 0; o < 7; ++o) {
      double a = e[o] * inv;
      sAB[p * 8 + o] = a;
      out[OUT_AB + (size_t)gp * 7 + o] = (float)a;
    }
    /* dominant: argmax over abundances[:5] == argmax over logits[:5] (softmax monotone) */
    int best = 0; double bv = lo[p * 8 + 0];
    #pragma unroll
    for (int k = 1; k < 5; ++k)
      if (lo[p * 8 + k] > bv) { bv = lo[p * 8 + k]; best = k; }
    #pragma unroll
    for (int k = 0; k < 5; ++k) ids_s[p * 5 + k] = cids[(size_t)gp * 5 + k];
    out[OUT_DOM + gp] = (float)ids_s[p * 5 + best];
  }
  __syncthreads();

  { /* recon: 16 threads per pixel, 14 bands each */
    const int p = t >> 4, l16 = t & 15;
    const int gp = pb + p, bz = l16 * 14;
    double r[14];
    #pragma unroll
    for (int j = 0; j < 14; ++j) r[j] = 0.0;
    #pragma unroll
    for (int k = 0; k < 5; ++k) {
      const int idk = ids_s[p * 5 + k];
      const double a = sAB[p * 8 + k];
      const float* pr = proto + (size_t)idk * NB + bz;
      #pragma unroll
      for (int j = 0; j < 14; ++j) r[j] = fma(a, (double)pr[j], r[j]);
    }
    #pragma unroll
    for (int j = 0; j < 14; ++j) out[OUT_RE + (size_t)gp * NB + bz + j] = (float)r[j];
  }
}

extern "C" void kernel_launch(void* const* d_in, const int* in_sizes, int n_in,
                              void* d_out, int out_size, void* d_ws, size_t ws_size,
                              hipStream_t stream) {
  (void)in_sizes; (void)n_in; (void)out_size; (void)ws_size;
  const float* feat  = (const float*)d_in[0];
  const float* w1_s  = (const float*)d_in[1];
  const float* b1_s  = (const float*)d_in[2];
  const float* w2_s  = (const float*)d_in[3];
  const float* b2_s  = (const float*)d_in[4];
  const float* w1_a  = (const float*)d_in[5];
  const float* b1_a  = (const float*)d_in[6];
  const float* w2_a  = (const float*)d_in[7];
  const float* b2_a  = (const float*)d_in[8];
  const float* lab   = (const float*)d_in[9];
  const float* proto = (const float*)d_in[10];
  float* out = (float*)d_out;
  char* ws = (char*)d_ws;
  double* wscores = (double*)(ws + WS_SCORES);
  float*  winvl   = (float*)(ws + WS_INVL);
  int*    wids8   = (int*)(ws + WS_IDS8);
  int*    wcids   = (int*)(ws + WS_CIDS);

  (void)hipFuncSetAttribute(reinterpret_cast<const void*>(sims_topk_kernel),
                            hipFuncAttributeMaxDynamicSharedMemorySize, 131072);

  libnorm_kernel<<<dim3(NLIB), dim3(64), 0, stream>>>(lab, winvl);
  score_mlp_kernel<<<dim3(P_TOT / 16), dim3(256), 0, stream>>>(
      feat, w1_s, b1_s, w2_s, b2_s, wscores);
  sims_topk_kernel<<<dim3(P_TOT / BM), dim3(512), 131072, stream>>>(
      feat, lab, winvl, wids8);
  refine_kernel<<<dim3(P_TOT / 4), dim3(256), 0, stream>>>(
      feat, lab, wids8, out, wcids);
  abund_kernel<<<dim3(P_TOT / 16), dim3(256), 0, stream>>>(
      feat, wscores, w1_a, b1_a, w2_a, b2_a, proto, wcids, out);
}

// Round 4
// 4587.325 us; speedup vs baseline: 1.4442x; 1.4442x over previous
//
#include <hip/hip_runtime.h>
#include <math.h>

#define EMB 256
#define HID 512
#define KTOP 5
#define NLIB 16384
#define NB 224
#define P_TOT 32768

/* d_out float layout: [P] dominant | [P][7] abundances | [P][224] recon | [P][5] cand_sims */
#define OUT_DOM ((size_t)0)
#define OUT_AB  ((size_t)P_TOT)
#define OUT_RE  ((size_t)8 * P_TOT)
#define OUT_CS  ((size_t)232 * P_TOT)

/* ws byte layout */
#define WS_SCORES 0                              /* P*5 double   = 1310720 */
#define WS_INVL   (P_TOT * KTOP * 8)             /* NLIB float   = 65536   */
#define WS_IDS8   (WS_INVL + NLIB * 4)           /* P*8 int      = 1048576 */
#define WS_CIDS   (WS_IDS8 + P_TOT * 8 * 4)      /* P*5 int      = 655360  */
#define WS_LABHI  (WS_CIDS + P_TOT * 5 * 4)      /* 8*NLIB*32 us = 8388608 */
#define WS_LABLO  (WS_LABHI + 8 * NLIB * 32 * 2) /* 8388608 */

typedef __attribute__((ext_vector_type(8))) short short8;
typedef __attribute__((ext_vector_type(4))) float f32x4;

__device__ __forceinline__ unsigned short f2bf(float x) {
  unsigned int u = __float_as_uint(x);
  u += 0x7fffu + ((u >> 16) & 1u);     /* RNE */
  return (unsigned short)(u >> 16);
}
__device__ __forceinline__ float bf2f(unsigned short b) {
  return __uint_as_float(((unsigned int)b) << 16);
}

__device__ __forceinline__ bool better_(float v, int vi, float e, int ei) {
  return (v > e) || ((v == e) && (vi < ei));  /* jax top_k tie-break: lower id first */
}
__device__ __forceinline__ bool betterd_(double v, int vi, double e, int ei) {
  return (v > e) || ((v == e) && (vi < ei));
}

__device__ __forceinline__ void ins5_(float& s0, int& d0, float& s1, int& d1,
                                      float& s2, int& d2, float& s3, int& d3,
                                      float& s4, int& d4, float v, int vi) {
  if (!better_(v, vi, s4, d4)) return;
  s4 = v; d4 = vi;
  if (better_(s4, d4, s3, d3)) {
    float tf = s3; int td = d3; s3 = s4; d3 = d4; s4 = tf; d4 = td;
    if (better_(s3, d3, s2, d2)) {
      tf = s2; td = d2; s2 = s3; d2 = d3; s3 = tf; d3 = td;
      if (better_(s2, d2, s1, d1)) {
        tf = s1; td = d1; s1 = s2; d1 = d2; s2 = tf; d2 = td;
        if (better_(s1, d1, s0, d0)) {
          tf = s0; td = d0; s0 = s1; d0 = d1; s1 = tf; d1 = td;
        }
      }
    }
  }
}

__device__ __forceinline__ void ins8_(float m[8], int n[8], float v, int vi) {
  if (!better_(v, vi, m[7], n[7])) return;
  m[7] = v; n[7] = vi;
  #pragma unroll
  for (int q = 7; q >= 1; --q) {
    if (better_(m[q], n[q], m[q - 1], n[q - 1])) {
      float tf = m[q - 1]; m[q - 1] = m[q]; m[q] = tf;
      int td = n[q - 1]; n[q - 1] = n[q]; n[q] = td;
    }
  }
}

/* ---------------- kernel 0: split lab into bf16 hi/lo, k-tiled [8][NLIB][32] ---------------- */
__global__ __launch_bounds__(64) void labsplit_kernel(const float* __restrict__ lab,
                                                      unsigned short* __restrict__ hiT,
                                                      unsigned short* __restrict__ loT) {
  const int row = blockIdx.x;
  const int lane = threadIdx.x;
  float4 v = *(const float4*)(lab + (size_t)row * EMB + lane * 4);
  unsigned short h0 = f2bf(v.x), h1 = f2bf(v.y), h2 = f2bf(v.z), h3 = f2bf(v.w);
  unsigned short l0 = f2bf(v.x - bf2f(h0)), l1 = f2bf(v.y - bf2f(h1));
  unsigned short l2 = f2bf(v.z - bf2f(h2)), l3 = f2bf(v.w - bf2f(h3));
  const int kk = lane >> 3;              /* which 32-wide k-chunk */
  const int kp = (lane * 4) & 31;
  const size_t dst = (size_t)kk * (NLIB * 32) + (size_t)row * 32 + kp;
  ushort4 ph; ph.x = h0; ph.y = h1; ph.z = h2; ph.w = h3;
  ushort4 pl; pl.x = l0; pl.y = l1; pl.z = l2; pl.w = l3;
  *(ushort4*)(hiT + dst) = ph;
  *(ushort4*)(loT + dst) = pl;
}

/* ---------------- kernel 1: library row inverse norms (f32 fast path) ---------------- */
__global__ __launch_bounds__(64) void libnorm_kernel(const float* __restrict__ lab,
                                                     float* __restrict__ invl) {
  const int row = blockIdx.x;
  const int lane = threadIdx.x;
  float4 v = *(const float4*)(lab + (size_t)row * EMB + lane * 4);
  float s = v.x * v.x + v.y * v.y + v.z * v.z + v.w * v.w;
  #pragma unroll
  for (int off = 32; off >= 1; off >>= 1) s += __shfl_down(s, off);
  if (lane == 0) invl[row] = 1.0f / (sqrtf(s) + 1e-12f);
}

/* ------------- kernel 2: score MLP (256->512->5), f64 accumulation ------------- */
__global__ __launch_bounds__(256) void score_mlp_kernel(
    const float* __restrict__ feat, const float* __restrict__ w1,
    const float* __restrict__ b1, const float* __restrict__ w2,
    const float* __restrict__ b2, double* __restrict__ scores) {
  __shared__ __align__(16) float xs[16 * 264];
  __shared__ __align__(16) float hs[16 * 516];
  const int t = threadIdx.x;
  const int pb = blockIdx.x * 16;

  #pragma unroll
  for (int i = 0; i < 4; ++i) {
    int F = i * 256 + t;
    int p = F >> 6, q = (F & 63) * 4;
    *(float4*)&xs[p * 264 + q] = *(const float4*)(feat + (size_t)(pb + p) * EMB + q);
  }
  __syncthreads();

  const int h0 = t, h1 = t + 256;
  double a0[16], a1[16];
  #pragma unroll
  for (int p = 0; p < 16; ++p) { a0[p] = 0.0; a1[p] = 0.0; }

  for (int i4 = 0; i4 < 64; ++i4) {
    const int i = i4 * 4;
    double w00 = w1[(i + 0) * HID + h0], w01 = w1[(i + 1) * HID + h0];
    double w02 = w1[(i + 2) * HID + h0], w03 = w1[(i + 3) * HID + h0];
    double w10 = w1[(i + 0) * HID + h1], w11 = w1[(i + 1) * HID + h1];
    double w12 = w1[(i + 2) * HID + h1], w13 = w1[(i + 3) * HID + h1];
    #pragma unroll
    for (int p = 0; p < 16; ++p) {
      float4 x = *(const float4*)&xs[p * 264 + i];
      a0[p] = fma((double)x.x, w00, a0[p]); a0[p] = fma((double)x.y, w01, a0[p]);
      a0[p] = fma((double)x.z, w02, a0[p]); a0[p] = fma((double)x.w, w03, a0[p]);
      a1[p] = fma((double)x.x, w10, a1[p]); a1[p] = fma((double)x.y, w11, a1[p]);
      a1[p] = fma((double)x.z, w12, a1[p]); a1[p] = fma((double)x.w, w13, a1[p]);
    }
  }
  const double bb0 = b1[h0], bb1 = b1[h1];
  #pragma unroll
  for (int p = 0; p < 16; ++p) {
    hs[p * 516 + h0] = (float)fmax(a0[p] + bb0, 0.0);
    hs[p * 516 + h1] = (float)fmax(a1[p] + bb1, 0.0);
  }
  __syncthreads();

  if (t < 80) {
    const int p = t / 5, o = t % 5;
    double acc = (double)b2[o];
    for (int h4 = 0; h4 < 128; ++h4) {
      float4 hv = *(const float4*)&hs[p * 516 + h4 * 4];
      acc = fma((double)hv.x, (double)w2[(h4 * 4 + 0) * 5 + o], acc);
      acc = fma((double)hv.y, (double)w2[(h4 * 4 + 1) * 5 + o], acc);
      acc = fma((double)hv.z, (double)w2[(h4 * 4 + 2) * 5 + o], acc);
      acc = fma((double)hv.w, (double)w2[(h4 * 4 + 3) * 5 + o], acc);
    }
    scores[(size_t)(pb + p) * 5 + o] = acc;
  }
}

/* ------------- kernel 3: bf16x3-split MFMA sims + register top-5 → per-pixel top-8 -------------
 * C = lab @ feat^T per block: 64 px, full NLIB sweep. 8 waves × (64 libs × 64 px).
 * A = lab (M=libs), B = feat^T (N=px).  mfma_f32_16x16x32_bf16:
 *   A lane l: row=l&15, k=8*(l>>4)+e ; B lane l: col=l&15, k=8*(l>>4)+e
 *   C lane l: col=l&15 (px), row=(l>>4)*4+reg (lib)  → lane's sims all in 4 px lists.
 * LDS 128KB: fhi[64][32slot][16B] | flo | lhi[512][4slot][16B] | llo ; slots XOR-swizzled. */
__global__ __launch_bounds__(512, 2) void sims_topk_kernel(
    const float* __restrict__ feat, const unsigned short* __restrict__ labhiT,
    const unsigned short* __restrict__ labloT, const float* __restrict__ invl,
    int* __restrict__ ids8) {
  extern __shared__ char smem[];
  char* fhi = smem;                 /* 32 KB */
  char* flo = smem + 32 * 1024;     /* 32 KB */
  char* lhi = smem + 64 * 1024;     /* 32 KB */
  char* llo = smem + 96 * 1024;     /* 32 KB */
  const int t = threadIdx.x;
  const int l = t & 63, w = t >> 6;
  const int pb = blockIdx.x * 64;

  /* ---- stage features: f32 → bf16 hi/lo, swizzled slots ---- */
  {
    const int px = t >> 3, sg = t & 7;
    const float* src = feat + (size_t)(pb + px) * EMB;
    #pragma unroll
    for (int j = 0; j < 4; ++j) {
      const int slot = sg * 4 + j;
      float4 v0 = *(const float4*)(src + slot * 8);
      float4 v1 = *(const float4*)(src + slot * 8 + 4);
      float vv[8] = {v0.x, v0.y, v0.z, v0.w, v1.x, v1.y, v1.z, v1.w};
      unsigned int ph[4], pl[4];
      #pragma unroll
      for (int e = 0; e < 4; ++e) {
        unsigned short ha = f2bf(vv[2 * e]), hb = f2bf(vv[2 * e + 1]);
        unsigned short la = f2bf(vv[2 * e] - bf2f(ha));
        unsigned short lb = f2bf(vv[2 * e + 1] - bf2f(hb));
        ph[e] = (unsigned int)ha | ((unsigned int)hb << 16);
        pl[e] = (unsigned int)la | ((unsigned int)lb << 16);
      }
      const int so = (slot ^ (px & 7)) * 16;
      *(uint4*)(fhi + px * 512 + so) = make_uint4(ph[0], ph[1], ph[2], ph[3]);
      *(uint4*)(flo + px * 512 + so) = make_uint4(pl[0], pl[1], pl[2], pl[3]);
    }
  }

  f32x4 acc[4][4];
  #pragma unroll
  for (int mi = 0; mi < 4; ++mi)
    #pragma unroll
    for (int nj = 0; nj < 4; ++nj) acc[mi][nj] = (f32x4){0.f, 0.f, 0.f, 0.f};

  float ts[4][5]; int ti[4][5];
  #pragma unroll
  for (int nj = 0; nj < 4; ++nj)
    #pragma unroll
    for (int e = 0; e < 5; ++e) { ts[nj][e] = -3.0e38f; ti[nj][e] = 0x7fffffff; }

  /* prologue: load chunk (st=0, kk=0) into regs */
  uint4 rh[4], rl[4];
  {
    const uint4* hg = (const uint4*)(labhiT);
    const uint4* lg = (const uint4*)(labloT);
    #pragma unroll
    for (int j = 0; j < 4; ++j) { rh[j] = hg[j * 512 + t]; rl[j] = lg[j * 512 + t]; }
  }

  for (int it = 0; it < 256; ++it) {
    const int st = it >> 3, kk = it & 7;
    __syncthreads();          /* prev compute done reading lhi/llo (and F writes visible) */
    #pragma unroll
    for (int j = 0; j < 4; ++j) {
      const int idx = j * 512 + t;
      const int row = idx >> 2, sl = idx & 3;
      const int off = row * 64 + ((sl ^ (row & 3)) * 16);
      *(uint4*)(lhi + off) = rh[j];
      *(uint4*)(llo + off) = rl[j];
    }
    if (it + 1 < 256) {       /* issue next chunk loads; latency hides under compute */
      const int st1 = (it + 1) >> 3, kk1 = (it + 1) & 7;
      const uint4* hg = (const uint4*)(labhiT + (size_t)kk1 * (NLIB * 32) + (size_t)st1 * 512 * 32);
      const uint4* lg = (const uint4*)(labloT + (size_t)kk1 * (NLIB * 32) + (size_t)st1 * 512 * 32);
      #pragma unroll
      for (int j = 0; j < 4; ++j) { rh[j] = hg[j * 512 + t]; rl[j] = lg[j * 512 + t]; }
    }
    __syncthreads();          /* chunk ready */

    short8 ahi[4], alo[4];
    #pragma unroll
    for (int mi = 0; mi < 4; ++mi) {
      const int lrow = w * 64 + mi * 16 + (l & 15);
      const int off = lrow * 64 + (((l >> 4) ^ (lrow & 3)) * 16);
      ahi[mi] = *(const short8*)(lhi + off);
      alo[mi] = *(const short8*)(llo + off);
    }
    #pragma unroll
    for (int nj = 0; nj < 4; ++nj) {
      const int px = nj * 16 + (l & 15);
      const int boff = px * 512 + (((kk * 4 + (l >> 4)) ^ (l & 7)) * 16);
      const short8 bhi = *(const short8*)(fhi + boff);
      const short8 blo = *(const short8*)(flo + boff);
      #pragma unroll
      for (int mi = 0; mi < 4; ++mi) {
        acc[mi][nj] = __builtin_amdgcn_mfma_f32_16x16x32_bf16(ahi[mi], bhi, acc[mi][nj], 0, 0, 0);
        acc[mi][nj] = __builtin_amdgcn_mfma_f32_16x16x32_bf16(ahi[mi], blo, acc[mi][nj], 0, 0, 0);
        acc[mi][nj] = __builtin_amdgcn_mfma_f32_16x16x32_bf16(alo[mi], bhi, acc[mi][nj], 0, 0, 0);
      }
    }

    if (kk == 7) {            /* K done for this 512-lib super-tile: insert & reset */
      const int libb = st * 512 + w * 64 + (l >> 4) * 4;
      #pragma unroll
      for (int mi = 0; mi < 4; ++mi) {
        const f32x4 il = *(const f32x4*)(invl + libb + mi * 16);
        #pragma unroll
        for (int nj = 0; nj < 4; ++nj) {
          #pragma unroll
          for (int r = 0; r < 4; ++r) {
            const float v = acc[mi][nj][r] * il[r];
            const int id = libb + mi * 16 + r;
            ins5_(ts[nj][0], ti[nj][0], ts[nj][1], ti[nj][1], ts[nj][2], ti[nj][2],
                  ts[nj][3], ti[nj][3], ts[nj][4], ti[nj][4], v, id);
          }
          acc[mi][nj] = (f32x4){0.f, 0.f, 0.f, 0.f};
        }
      }
    }
  }

  /* ---- final merge: 32 lists × 5 per pixel → top-8 ---- */
  __syncthreads();
  float* simsL = (float*)smem;                    /* [64][161] */
  int* idsL = (int*)(smem + 64 * 161 * 4);        /* [64][161] */
  #pragma unroll
  for (int nj = 0; nj < 4; ++nj) {
    const int px = nj * 16 + (l & 15);
    const int col = (w * 4 + (l >> 4)) * 5;
    #pragma unroll
    for (int e = 0; e < 5; ++e) {
      simsL[px * 161 + col + e] = ts[nj][e];
      idsL[px * 161 + col + e] = ti[nj][e];
    }
  }
  __syncthreads();

  if (t < 64) {
    float m[8]; int n[8];
    #pragma unroll
    for (int j = 0; j < 8; ++j) { m[j] = -3.0e38f; n[j] = 0x7fffffff; }
    for (int c = 0; c < 160; ++c)
      ins8_(m, n, simsL[t * 161 + c], idsL[t * 161 + c]);
    const int gp = pb + t;
    #pragma unroll
    for (int j = 0; j < 8; ++j) ids8[(size_t)gp * 8 + j] = n[j];
  }
}

/* ------------- kernel 3b: exact f64 refinement of the 8 candidates ------------- */
__global__ __launch_bounds__(256) void refine_kernel(
    const float* __restrict__ feat, const float* __restrict__ lab,
    const int* __restrict__ ids8, float* __restrict__ out,
    int* __restrict__ cids) {
  const int t = threadIdx.x;
  const int lane = t & 63;
  const int p = blockIdx.x * 4 + (t >> 6);

  float4 f = *(const float4*)(feat + (size_t)p * EMB + lane * 4);
  const double fx = f.x, fy = f.y, fz = f.z, fw = f.w;
  double sf = fx * fx + fy * fy + fz * fz + fw * fw;

  int id[8];
  #pragma unroll
  for (int j = 0; j < 8; ++j) id[j] = ids8[(size_t)p * 8 + j];

  double dot[8], sl[8];
  #pragma unroll
  for (int j = 0; j < 8; ++j) {
    float4 lv = *(const float4*)(lab + (size_t)id[j] * EMB + lane * 4);
    const double lx = lv.x, ly = lv.y, lz = lv.z, lw = lv.w;
    dot[j] = fma(fx, lx, fma(fy, ly, fma(fz, lz, fw * lw)));
    sl[j]  = fma(lx, lx, fma(ly, ly, fma(lz, lz, lw * lw)));
  }
  #pragma unroll
  for (int off = 32; off >= 1; off >>= 1) {
    sf += __shfl_xor(sf, off);
    #pragma unroll
    for (int j = 0; j < 8; ++j) {
      dot[j] += __shfl_xor(dot[j], off);
      sl[j]  += __shfl_xor(sl[j], off);
    }
  }
  if (lane == 0) {
    const double invf = 1.0 / (sqrt(sf) + 1e-12);
    double s[8];
    #pragma unroll
    for (int j = 0; j < 8; ++j)
      s[j] = dot[j] * (1.0 / (sqrt(sl[j]) + 1e-12)) * invf;
    #pragma unroll
    for (int pass = 0; pass < 7; ++pass) {
      #pragma unroll
      for (int i = 0; i < 7; ++i) {
        if (i < 7 - pass) {
          if (betterd_(s[i + 1], id[i + 1], s[i], id[i])) {
            double tv = s[i]; s[i] = s[i + 1]; s[i + 1] = tv;
            int td = id[i]; id[i] = id[i + 1]; id[i + 1] = td;
          }
        }
      }
    }
    #pragma unroll
    for (int k = 0; k < 5; ++k) {
      out[OUT_CS + (size_t)p * 5 + k] = (float)s[k];
      cids[(size_t)p * 5 + k] = id[k];
    }
  }
}

/* ------------- kernel 4: abundance MLP (f64) + softmax + recon + dominant ------------- */
__global__ __launch_bounds__(256) void abund_kernel(
    const float* __restrict__ feat, const double* __restrict__ scores,
    const float* __restrict__ w1, const float* __restrict__ b1,
    const float* __restrict__ w2, const float* __restrict__ b2,
    const float* __restrict__ proto, const int* __restrict__ cids,
    float* __restrict__ out) {
  __shared__ __align__(16) float xs[16 * 264];
  __shared__ __align__(16) float hs[16 * 520];
  __shared__ double scs[16 * 5];
  __shared__ double lo[16 * 8];
  __shared__ double sAB[16 * 8];
  __shared__ int ids_s[16 * 5];
  const int t = threadIdx.x;
  const int pb = blockIdx.x * 16;

  #pragma unroll
  for (int i = 0; i < 4; ++i) {
    int F = i * 256 + t;
    int p = F >> 6, q = (F & 63) * 4;
    *(float4*)&xs[p * 264 + q] = *(const float4*)(feat + (size_t)(pb + p) * EMB + q);
  }
  if (t < 80) scs[t] = scores[(size_t)(pb + t / 5) * 5 + (t % 5)];
  __syncthreads();

  const int h0 = t, h1 = t + 256;
  double a0[16], a1[16];
  #pragma unroll
  for (int p = 0; p < 16; ++p) { a0[p] = 0.0; a1[p] = 0.0; }

  for (int i4 = 0; i4 < 64; ++i4) {
    const int i = i4 * 4;
    double w00 = w1[(i + 0) * HID + h0], w01 = w1[(i + 1) * HID + h0];
    double w02 = w1[(i + 2) * HID + h0], w03 = w1[(i + 3) * HID + h0];
    double w10 = w1[(i + 0) * HID + h1], w11 = w1[(i + 1) * HID + h1];
    double w12 = w1[(i + 2) * HID + h1], w13 = w1[(i + 3) * HID + h1];
    #pragma unroll
    for (int p = 0; p < 16; ++p) {
      float4 x = *(const float4*)&xs[p * 264 + i];
      a0[p] = fma((double)x.x, w00, a0[p]); a0[p] = fma((double)x.y, w01, a0[p]);
      a0[p] = fma((double)x.z, w02, a0[p]); a0[p] = fma((double)x.w, w03, a0[p]);
      a1[p] = fma((double)x.x, w10, a1[p]); a1[p] = fma((double)x.y, w11, a1[p]);
      a1[p] = fma((double)x.z, w12, a1[p]); a1[p] = fma((double)x.w, w13, a1[p]);
    }
  }
  #pragma unroll
  for (int r = 0; r < 5; ++r) {
    double wA = w1[(256 + r) * HID + h0], wB = w1[(256 + r) * HID + h1];
    #pragma unroll
    for (int p = 0; p < 16; ++p) {
      double x = scs[p * 5 + r];
      a0[p] = fma(x, wA, a0[p]);
      a1[p] = fma(x, wB, a1[p]);
    }
  }
  const double bb0 = b1[h0], bb1 = b1[h1];
  #pragma unroll
  for (int p = 0; p < 16; ++p) {
    hs[p * 520 + h0] = (float)fmax(a0[p] + bb0, 0.0);
    hs[p * 520 + h1] = (float)fmax(a1[p] + bb1, 0.0);
  }
  __syncthreads();

  if (t < 112) {
    const int p = t / 7, o = t % 7;
    double acc = (double)b2[o];
    for (int h4 = 0; h4 < 128; ++h4) {
      float4 hv = *(const float4*)&hs[p * 520 + h4 * 4];
      acc = fma((double)hv.x, (double)w2[(h4 * 4 + 0) * 7 + o], acc);
      acc = fma((double)hv.y, (double)w2[(h4 * 4 + 1) * 7 + o], acc);
      acc = fma((double)hv.z, (double)w2[(h4 * 4 + 2) * 7 + o], acc);
      acc = fma((double)hv.w, (double)w2[(h4 * 4 + 3) * 7 + o], acc);
    }
    lo[p * 8 + o] = acc;
  }
  __syncthreads();

  if (t < 16) {
    const int p = t, gp = pb + t;
    double m = lo[p * 8 + 0];
    #pragma unroll
    for (int o = 1; o < 7; ++o) m = fmax(m, lo[p * 8 + o]);
    double e[7]; double ssum = 0.0;
    #pragma unroll
    for (int o = 0; o < 7; ++o) { e[o] = exp(lo[p * 8 + o] - m); ssum += e[o]; }
    const double inv = 1.0 / ssum;
    #pragma unroll
    for (int o = 0; o < 7; ++o) {
      double a = e[o] * inv;
      sAB[p * 8 + o] = a;
      out[OUT_AB + (size_t)gp * 7 + o] = (float)a;
    }
    int best = 0; double bv = lo[p * 8 + 0];
    #pragma unroll
    for (int k = 1; k < 5; ++k)
      if (lo[p * 8 + k] > bv) { bv = lo[p * 8 + k]; best = k; }
    #pragma unroll
    for (int k = 0; k < 5; ++k) ids_s[p * 5 + k] = cids[(size_t)gp * 5 + k];
    out[OUT_DOM + gp] = (float)ids_s[p * 5 + best];
  }
  __syncthreads();

  {
    const int p = t >> 4, l16 = t & 15;
    const int gp = pb + p, bz = l16 * 14;
    double r[14];
    #pragma unroll
    for (int j = 0; j < 14; ++j) r[j] = 0.0;
    #pragma unroll
    for (int k = 0; k < 5; ++k) {
      const int idk = ids_s[p * 5 + k];
      const double a = sAB[p * 8 + k];
      const float* pr = proto + (size_t)idk * NB + bz;
      #pragma unroll
      for (int j = 0; j < 14; ++j) r[j] = fma(a, (double)pr[j], r[j]);
    }
    #pragma unroll
    for (int j = 0; j < 14; ++j) out[OUT_RE + (size_t)gp * NB + bz + j] = (float)r[j];
  }
}

extern "C" void kernel_launch(void* const* d_in, const int* in_sizes, int n_in,
                              void* d_out, int out_size, void* d_ws, size_t ws_size,
                              hipStream_t stream) {
  (void)in_sizes; (void)n_in; (void)out_size; (void)ws_size;
  const float* feat  = (const float*)d_in[0];
  const float* w1_s  = (const float*)d_in[1];
  const float* b1_s  = (const float*)d_in[2];
  const float* w2_s  = (const float*)d_in[3];
  const float* b2_s  = (const float*)d_in[4];
  const float* w1_a  = (const float*)d_in[5];
  const float* b1_a  = (const float*)d_in[6];
  const float* w2_a  = (const float*)d_in[7];
  const float* b2_a  = (const float*)d_in[8];
  const float* lab   = (const float*)d_in[9];
  const float* proto = (const float*)d_in[10];
  float* out = (float*)d_out;
  char* ws = (char*)d_ws;
  double* wscores = (double*)(ws + WS_SCORES);
  float*  winvl   = (float*)(ws + WS_INVL);
  int*    wids8   = (int*)(ws + WS_IDS8);
  int*    wcids   = (int*)(ws + WS_CIDS);
  unsigned short* wlabhi = (unsigned short*)(ws + WS_LABHI);
  unsigned short* wlablo = (unsigned short*)(ws + WS_LABLO);

  (void)hipFuncSetAttribute(reinterpret_cast<const void*>(sims_topk_kernel),
                            hipFuncAttributeMaxDynamicSharedMemorySize, 131072);

  labsplit_kernel<<<dim3(NLIB), dim3(64), 0, stream>>>(lab, wlabhi, wlablo);
  libnorm_kernel<<<dim3(NLIB), dim3(64), 0, stream>>>(lab, winvl);
  score_mlp_kernel<<<dim3(P_TOT / 16), dim3(256), 0, stream>>>(
      feat, w1_s, b1_s, w2_s, b2_s, wscores);
  sims_topk_kernel<<<dim3(P_TOT / 64), dim3(512), 131072, stream>>>(
      feat, wlabhi, wlablo, winvl, wids8);
  refine_kernel<<<dim3(P_TOT / 4), dim3(256), 0, stream>>>(
      feat, lab, wids8, out, wcids);
  abund_kernel<<<dim3(P_TOT / 16), dim3(256), 0, stream>>>(
      feat, wscores, w1_a, b1_a, w2_a, b2_a, proto, wcids, out);
}

// Round 5
// 2857.790 us; speedup vs baseline: 2.3182x; 1.6052x over previous
//
#include <hip/hip_runtime.h>
#include <math.h>

#define EMB 256
#define HID 512
#define KTOP 5
#define NLIB 16384
#define NB 224
#define P_TOT 32768

/* d_out float layout: [P] dominant | [P][7] abundances | [P][224] recon | [P][5] cand_sims */
#define OUT_DOM ((size_t)0)
#define OUT_AB  ((size_t)P_TOT)
#define OUT_RE  ((size_t)8 * P_TOT)
#define OUT_CS  ((size_t)232 * P_TOT)

/* ws byte layout */
#define WS_SCORES 0                              /* P*5 double   = 1310720 */
#define WS_INVL   (P_TOT * KTOP * 8)             /* NLIB float   = 65536   */
#define WS_IDS8   (WS_INVL + NLIB * 4)           /* P*8 int      = 1048576 */
#define WS_CIDS   (WS_IDS8 + P_TOT * 8 * 4)      /* P*5 int      = 655360  */
#define WS_LAB    (WS_CIDS + P_TOT * 5 * 4)      /* 512 chunks * 32KB = 16 MB (LDS images) */

typedef __attribute__((ext_vector_type(8))) short short8;
typedef __attribute__((ext_vector_type(4))) float f32x4;

__device__ __forceinline__ unsigned short f2bf(float x) {
  unsigned int u = __float_as_uint(x);
  u += 0x7fffu + ((u >> 16) & 1u);     /* RNE */
  return (unsigned short)(u >> 16);
}
__device__ __forceinline__ float bf2f(unsigned short b) {
  return __uint_as_float(((unsigned int)b) << 16);
}

__device__ __forceinline__ bool better_(float v, int vi, float e, int ei) {
  return (v > e) || ((v == e) && (vi < ei));  /* jax top_k tie-break: lower id first */
}
__device__ __forceinline__ bool betterd_(double v, int vi, double e, int ei) {
  return (v > e) || ((v == e) && (vi < ei));
}

__device__ __forceinline__ void ins5_(float& s0, int& d0, float& s1, int& d1,
                                      float& s2, int& d2, float& s3, int& d3,
                                      float& s4, int& d4, float v, int vi) {
  if (!better_(v, vi, s4, d4)) return;
  s4 = v; d4 = vi;
  if (better_(s4, d4, s3, d3)) {
    float tf = s3; int td = d3; s3 = s4; d3 = d4; s4 = tf; d4 = td;
    if (better_(s3, d3, s2, d2)) {
      tf = s2; td = d2; s2 = s3; d2 = d3; s3 = tf; d3 = td;
      if (better_(s2, d2, s1, d1)) {
        tf = s1; td = d1; s1 = s2; d1 = d2; s2 = tf; d2 = td;
        if (better_(s1, d1, s0, d0)) {
          tf = s0; td = d0; s0 = s1; d0 = d1; s1 = tf; d1 = td;
        }
      }
    }
  }
}

__device__ __forceinline__ void ins8_(float m[8], int n[8], float v, int vi) {
  if (!better_(v, vi, m[7], n[7])) return;
  m[7] = v; n[7] = vi;
  #pragma unroll
  for (int q = 7; q >= 1; --q) {
    if (better_(m[q], n[q], m[q - 1], n[q - 1])) {
      float tf = m[q - 1]; m[q - 1] = m[q]; m[q] = tf;
      int td = n[q - 1]; n[q - 1] = n[q]; n[q] = td;
    }
  }
}

/* ---------------- kernel 0: split lab into bf16 hi/lo LDS-image chunks ----------------
 * chunk c = (row>>8)*8 + (k>>5): 256 rows x 32 k, 32 KB = [hi 16KB][lo 16KB].
 * within plane: byte = rr*64 + (slot_log ^ ((rr>>1)&3))*16 + elem*2   (A-read swizzle, 2-way max) */
__global__ __launch_bounds__(64) void labsplit_kernel(const float* __restrict__ lab,
                                                      char* __restrict__ wslab) {
  const int row = blockIdx.x;
  const int lane = threadIdx.x;        /* handles k = lane*4 .. lane*4+3 */
  float4 v = *(const float4*)(lab + (size_t)row * EMB + lane * 4);
  ushort4 ph, pl;
  ph.x = f2bf(v.x); pl.x = f2bf(v.x - bf2f(ph.x));
  ph.y = f2bf(v.y); pl.y = f2bf(v.y - bf2f(ph.y));
  ph.z = f2bf(v.z); pl.z = f2bf(v.z - bf2f(ph.z));
  ph.w = f2bf(v.w); pl.w = f2bf(v.w - bf2f(ph.w));
  const int rr = row & 255;
  const int chunk = (row >> 8) * 8 + (lane >> 3);
  const int slot_log = (lane & 7) >> 1;
  const int phys = slot_log ^ ((rr >> 1) & 3);
  const size_t base = (size_t)chunk * 32768 + (size_t)rr * 64 + phys * 16 + (lane & 1) * 8;
  *(ushort4*)(wslab + base) = ph;
  *(ushort4*)(wslab + base + 16384) = pl;
}

/* ---------------- kernel 1: library row inverse norms (f32 fast path) ---------------- */
__global__ __launch_bounds__(64) void libnorm_kernel(const float* __restrict__ lab,
                                                     float* __restrict__ invl) {
  const int row = blockIdx.x;
  const int lane = threadIdx.x;
  float4 v = *(const float4*)(lab + (size_t)row * EMB + lane * 4);
  float s = v.x * v.x + v.y * v.y + v.z * v.z + v.w * v.w;
  #pragma unroll
  for (int off = 32; off >= 1; off >>= 1) s += __shfl_down(s, off);
  if (lane == 0) invl[row] = 1.0f / (sqrtf(s) + 1e-12f);
}

/* ------------- kernel 2: score MLP (256->512->5), f64 accumulation ------------- */
__global__ __launch_bounds__(256) void score_mlp_kernel(
    const float* __restrict__ feat, const float* __restrict__ w1,
    const float* __restrict__ b1, const float* __restrict__ w2,
    const float* __restrict__ b2, double* __restrict__ scores) {
  __shared__ __align__(16) float xs[16 * 264];
  __shared__ __align__(16) float hs[16 * 516];
  const int t = threadIdx.x;
  const int pb = blockIdx.x * 16;

  #pragma unroll
  for (int i = 0; i < 4; ++i) {
    int F = i * 256 + t;
    int p = F >> 6, q = (F & 63) * 4;
    *(float4*)&xs[p * 264 + q] = *(const float4*)(feat + (size_t)(pb + p) * EMB + q);
  }
  __syncthreads();

  const int h0 = t, h1 = t + 256;
  double a0[16], a1[16];
  #pragma unroll
  for (int p = 0; p < 16; ++p) { a0[p] = 0.0; a1[p] = 0.0; }

  for (int i4 = 0; i4 < 64; ++i4) {
    const int i = i4 * 4;
    double w00 = w1[(i + 0) * HID + h0], w01 = w1[(i + 1) * HID + h0];
    double w02 = w1[(i + 2) * HID + h0], w03 = w1[(i + 3) * HID + h0];
    double w10 = w1[(i + 0) * HID + h1], w11 = w1[(i + 1) * HID + h1];
    double w12 = w1[(i + 2) * HID + h1], w13 = w1[(i + 3) * HID + h1];
    #pragma unroll
    for (int p = 0; p < 16; ++p) {
      float4 x = *(const float4*)&xs[p * 264 + i];
      a0[p] = fma((double)x.x, w00, a0[p]); a0[p] = fma((double)x.y, w01, a0[p]);
      a0[p] = fma((double)x.z, w02, a0[p]); a0[p] = fma((double)x.w, w03, a0[p]);
      a1[p] = fma((double)x.x, w10, a1[p]); a1[p] = fma((double)x.y, w11, a1[p]);
      a1[p] = fma((double)x.z, w12, a1[p]); a1[p] = fma((double)x.w, w13, a1[p]);
    }
  }
  const double bb0 = b1[h0], bb1 = b1[h1];
  #pragma unroll
  for (int p = 0; p < 16; ++p) {
    hs[p * 516 + h0] = (float)fmax(a0[p] + bb0, 0.0);
    hs[p * 516 + h1] = (float)fmax(a1[p] + bb1, 0.0);
  }
  __syncthreads();

  if (t < 80) {
    const int p = t / 5, o = t % 5;
    double acc = (double)b2[o];
    for (int h4 = 0; h4 < 128; ++h4) {
      float4 hv = *(const float4*)&hs[p * 516 + h4 * 4];
      acc = fma((double)hv.x, (double)w2[(h4 * 4 + 0) * 5 + o], acc);
      acc = fma((double)hv.y, (double)w2[(h4 * 4 + 1) * 5 + o], acc);
      acc = fma((double)hv.z, (double)w2[(h4 * 4 + 2) * 5 + o], acc);
      acc = fma((double)hv.w, (double)w2[(h4 * 4 + 3) * 5 + o], acc);
    }
    scores[(size_t)(pb + p) * 5 + o] = acc;
  }
}

/* ------------- kernel 3: bf16x3-split MFMA sims + register top-5 → per-pixel top-8 -------------
 * Per block: 64 px, full NLIB sweep; 8 waves, wave tile = 32 libs x 64 px per chunk.
 * Chunk = 256 libs x 32 k, staged via global_load_lds from pre-swizzled ws image, dbuf.
 * C lane l: col=l&15 (px), row=(l>>4)*4+reg (lib) → per-lane top-5 lists stay in registers.
 * LDS 128KB: fhi 32K | flo 32K | labbuf0 32K | labbuf1 32K. */
__global__ __launch_bounds__(512, 2) void sims_topk_kernel(
    const float* __restrict__ feat, const char* __restrict__ wslab,
    const float* __restrict__ invl, int* __restrict__ ids8) {
  extern __shared__ char smem[];
  char* fhi = smem;                   /* [64 px][32 slot][16B], slot^=(px&7) */
  char* flo = smem + 32 * 1024;
  char* lbuf0 = smem + 64 * 1024;     /* [hi 16K][lo 16K] per chunk image */
  char* lbuf1 = smem + 96 * 1024;
  const int t = threadIdx.x;
  const int l = t & 63, w = t >> 6;
  const int pb = blockIdx.x * 64;

  /* ---- stage features: f32 → bf16 hi/lo, swizzled slots ---- */
  {
    const int px = t >> 3, sg = t & 7;
    const float* src = feat + (size_t)(pb + px) * EMB;
    #pragma unroll
    for (int j = 0; j < 4; ++j) {
      const int slot = sg * 4 + j;
      float4 v0 = *(const float4*)(src + slot * 8);
      float4 v1 = *(const float4*)(src + slot * 8 + 4);
      float vv[8] = {v0.x, v0.y, v0.z, v0.w, v1.x, v1.y, v1.z, v1.w};
      unsigned int ph[4], pl[4];
      #pragma unroll
      for (int e = 0; e < 4; ++e) {
        unsigned short ha = f2bf(vv[2 * e]), hb = f2bf(vv[2 * e + 1]);
        unsigned short la = f2bf(vv[2 * e] - bf2f(ha));
        unsigned short lb = f2bf(vv[2 * e + 1] - bf2f(hb));
        ph[e] = (unsigned int)ha | ((unsigned int)hb << 16);
        pl[e] = (unsigned int)la | ((unsigned int)lb << 16);
      }
      const int so = (slot ^ (px & 7)) * 16;
      *(uint4*)(fhi + px * 512 + so) = make_uint4(ph[0], ph[1], ph[2], ph[3]);
      *(uint4*)(flo + px * 512 + so) = make_uint4(pl[0], pl[1], pl[2], pl[3]);
    }
  }

  f32x4 acc[2][4];
  #pragma unroll
  for (int mi = 0; mi < 2; ++mi)
    #pragma unroll
    for (int nj = 0; nj < 4; ++nj) acc[mi][nj] = (f32x4){0.f, 0.f, 0.f, 0.f};

  float ts[4][5]; int ti[4][5];
  #pragma unroll
  for (int nj = 0; nj < 4; ++nj)
    #pragma unroll
    for (int e = 0; e < 5; ++e) { ts[nj][e] = -3.0e38f; ti[nj][e] = 0x7fffffff; }

  /* prologue: async-stage chunk 0 → lbuf0 (8 waves x 4 KB, linear lane*16) */
  {
    const char* g = wslab;
    #pragma unroll
    for (int i = 0; i < 4; ++i) {
      const int off = w * 4096 + i * 1024;
      __builtin_amdgcn_global_load_lds(
          (const __attribute__((address_space(1))) unsigned int*)(g + off + l * 16),
          (__attribute__((address_space(3))) unsigned int*)(lbuf0 + off), 16, 0, 0);
    }
  }
  __syncthreads();   /* drains vmcnt + feat ds_writes */

  for (int it = 0; it < 512; ++it) {
    const int st = it >> 3, kk = it & 7;
    char* cur = (it & 1) ? lbuf1 : lbuf0;
    char* nxt = (it & 1) ? lbuf0 : lbuf1;

    if (it + 1 < 512) {   /* async prefetch next chunk; lands by end-of-iter barrier */
      const char* g = wslab + (size_t)(it + 1) * 32768;
      #pragma unroll
      for (int i = 0; i < 4; ++i) {
        const int off = w * 4096 + i * 1024;
        __builtin_amdgcn_global_load_lds(
            (const __attribute__((address_space(1))) unsigned int*)(g + off + l * 16),
            (__attribute__((address_space(3))) unsigned int*)(nxt + off), 16, 0, 0);
      }
    }

    /* A frags: rows w*32 + mi*16 + (l&15), k-group l>>4 */
    short8 ahi[2], alo[2];
    #pragma unroll
    for (int mi = 0; mi < 2; ++mi) {
      const int row = w * 32 + mi * 16 + (l & 15);
      const int off = row * 64 + (((l >> 4) ^ ((row >> 1) & 3)) * 16);
      ahi[mi] = *(const short8*)(cur + off);
      alo[mi] = *(const short8*)(cur + 16384 + off);
    }
    #pragma unroll
    for (int nj = 0; nj < 4; ++nj) {
      const int px = nj * 16 + (l & 15);
      const int boff = px * 512 + (((kk * 4 + (l >> 4)) ^ (px & 7)) * 16);
      const short8 bhi = *(const short8*)(fhi + boff);
      const short8 blo = *(const short8*)(flo + boff);
      #pragma unroll
      for (int mi = 0; mi < 2; ++mi) {
        acc[mi][nj] = __builtin_amdgcn_mfma_f32_16x16x32_bf16(ahi[mi], bhi, acc[mi][nj], 0, 0, 0);
        acc[mi][nj] = __builtin_amdgcn_mfma_f32_16x16x32_bf16(ahi[mi], blo, acc[mi][nj], 0, 0, 0);
        acc[mi][nj] = __builtin_amdgcn_mfma_f32_16x16x32_bf16(alo[mi], bhi, acc[mi][nj], 0, 0, 0);
      }
    }

    if (kk == 7) {        /* 256-lib super-tile complete: normalize, insert, reset */
      const int libb = st * 256 + w * 32 + (l >> 4) * 4;
      #pragma unroll
      for (int mi = 0; mi < 2; ++mi) {
        const f32x4 il = *(const f32x4*)(invl + libb + mi * 16);
        #pragma unroll
        for (int nj = 0; nj < 4; ++nj) {
          #pragma unroll
          for (int r = 0; r < 4; ++r) {
            const float v = acc[mi][nj][r] * il[r];
            const int id = libb + mi * 16 + r;
            ins5_(ts[nj][0], ti[nj][0], ts[nj][1], ti[nj][1], ts[nj][2], ti[nj][2],
                  ts[nj][3], ti[nj][3], ts[nj][4], ti[nj][4], v, id);
          }
          acc[mi][nj] = (f32x4){0.f, 0.f, 0.f, 0.f};
        }
      }
    }
    __syncthreads();      /* next chunk landed; cur free for overwrite next iter */
  }

  /* ---- final merge: 32 lists × 5 per pixel → top-8 ---- */
  float* simsL = (float*)smem;                    /* [64][161] */
  int* idsL = (int*)(smem + 64 * 161 * 4);        /* [64][161] */
  #pragma unroll
  for (int nj = 0; nj < 4; ++nj) {
    const int px = nj * 16 + (l & 15);
    const int col = (w * 4 + (l >> 4)) * 5;
    #pragma unroll
    for (int e = 0; e < 5; ++e) {
      simsL[px * 161 + col + e] = ts[nj][e];
      idsL[px * 161 + col + e] = ti[nj][e];
    }
  }
  __syncthreads();

  if (t < 64) {
    float m[8]; int n[8];
    #pragma unroll
    for (int j = 0; j < 8; ++j) { m[j] = -3.0e38f; n[j] = 0x7fffffff; }
    for (int c = 0; c < 160; ++c)
      ins8_(m, n, simsL[t * 161 + c], idsL[t * 161 + c]);
    const int gp = pb + t;
    #pragma unroll
    for (int j = 0; j < 8; ++j) ids8[(size_t)gp * 8 + j] = n[j];
  }
}

/* ------------- kernel 3b: exact f64 refinement of the 8 candidates ------------- */
__global__ __launch_bounds__(256) void refine_kernel(
    const float* __restrict__ feat, const float* __restrict__ lab,
    const int* __restrict__ ids8, float* __restrict__ out,
    int* __restrict__ cids) {
  const int t = threadIdx.x;
  const int lane = t & 63;
  const int p = blockIdx.x * 4 + (t >> 6);

  float4 f = *(const float4*)(feat + (size_t)p * EMB + lane * 4);
  const double fx = f.x, fy = f.y, fz = f.z, fw = f.w;
  double sf = fx * fx + fy * fy + fz * fz + fw * fw;

  int id[8];
  #pragma unroll
  for (int j = 0; j < 8; ++j) id[j] = ids8[(size_t)p * 8 + j];

  double dot[8], sl[8];
  #pragma unroll
  for (int j = 0; j < 8; ++j) {
    float4 lv = *(const float4*)(lab + (size_t)id[j] * EMB + lane * 4);
    const double lx = lv.x, ly = lv.y, lz = lv.z, lw = lv.w;
    dot[j] = fma(fx, lx, fma(fy, ly, fma(fz, lz, fw * lw)));
    sl[j]  = fma(lx, lx, fma(ly, ly, fma(lz, lz, lw * lw)));
  }
  #pragma unroll
  for (int off = 32; off >= 1; off >>= 1) {
    sf += __shfl_xor(sf, off);
    #pragma unroll
    for (int j = 0; j < 8; ++j) {
      dot[j] += __shfl_xor(dot[j], off);
      sl[j]  += __shfl_xor(sl[j], off);
    }
  }
  if (lane == 0) {
    const double invf = 1.0 / (sqrt(sf) + 1e-12);
    double s[8];
    #pragma unroll
    for (int j = 0; j < 8; ++j)
      s[j] = dot[j] * (1.0 / (sqrt(sl[j]) + 1e-12)) * invf;
    #pragma unroll
    for (int pass = 0; pass < 7; ++pass) {
      #pragma unroll
      for (int i = 0; i < 7; ++i) {
        if (i < 7 - pass) {
          if (betterd_(s[i + 1], id[i + 1], s[i], id[i])) {
            double tv = s[i]; s[i] = s[i + 1]; s[i + 1] = tv;
            int td = id[i]; id[i] = id[i + 1]; id[i + 1] = td;
          }
        }
      }
    }
    #pragma unroll
    for (int k = 0; k < 5; ++k) {
      out[OUT_CS + (size_t)p * 5 + k] = (float)s[k];
      cids[(size_t)p * 5 + k] = id[k];
    }
  }
}

/* ------------- kernel 4: abundance MLP (f64) + softmax + recon + dominant ------------- */
__global__ __launch_bounds__(256) void abund_kernel(
    const float* __restrict__ feat, const double* __restrict__ scores,
    const float* __restrict__ w1, const float* __restrict__ b1,
    const float* __restrict__ w2, const float* __restrict__ b2,
    const float* __restrict__ proto, const int* __restrict__ cids,
    float* __restrict__ out) {
  __shared__ __align__(16) float xs[16 * 264];
  __shared__ __align__(16) float hs[16 * 520];
  __shared__ double scs[16 * 5];
  __shared__ double lo[16 * 8];
  __shared__ double sAB[16 * 8];
  __shared__ int ids_s[16 * 5];
  const int t = threadIdx.x;
  const int pb = blockIdx.x * 16;

  #pragma unroll
  for (int i = 0; i < 4; ++i) {
    int F = i * 256 + t;
    int p = F >> 6, q = (F & 63) * 4;
    *(float4*)&xs[p * 264 + q] = *(const float4*)(feat + (size_t)(pb + p) * EMB + q);
  }
  if (t < 80) scs[t] = scores[(size_t)(pb + t / 5) * 5 + (t % 5)];
  __syncthreads();

  const int h0 = t, h1 = t + 256;
  double a0[16], a1[16];
  #pragma unroll
  for (int p = 0; p < 16; ++p) { a0[p] = 0.0; a1[p] = 0.0; }

  for (int i4 = 0; i4 < 64; ++i4) {
    const int i = i4 * 4;
    double w00 = w1[(i + 0) * HID + h0], w01 = w1[(i + 1) * HID + h0];
    double w02 = w1[(i + 2) * HID + h0], w03 = w1[(i + 3) * HID + h0];
    double w10 = w1[(i + 0) * HID + h1], w11 = w1[(i + 1) * HID + h1];
    double w12 = w1[(i + 2) * HID + h1], w13 = w1[(i + 3) * HID + h1];
    #pragma unroll
    for (int p = 0; p < 16; ++p) {
      float4 x = *(const float4*)&xs[p * 264 + i];
      a0[p] = fma((double)x.x, w00, a0[p]); a0[p] = fma((double)x.y, w01, a0[p]);
      a0[p] = fma((double)x.z, w02, a0[p]); a0[p] = fma((double)x.w, w03, a0[p]);
      a1[p] = fma((double)x.x, w10, a1[p]); a1[p] = fma((double)x.y, w11, a1[p]);
      a1[p] = fma((double)x.z, w12, a1[p]); a1[p] = fma((double)x.w, w13, a1[p]);
    }
  }
  #pragma unroll
  for (int r = 0; r < 5; ++r) {
    double wA = w1[(256 + r) * HID + h0], wB = w1[(256 + r) * HID + h1];
    #pragma unroll
    for (int p = 0; p < 16; ++p) {
      double x = scs[p * 5 + r];
      a0[p] = fma(x, wA, a0[p]);
      a1[p] = fma(x, wB, a1[p]);
    }
  }
  const double bb0 = b1[h0], bb1 = b1[h1];
  #pragma unroll
  for (int p = 0; p < 16; ++p) {
    hs[p * 520 + h0] = (float)fmax(a0[p] + bb0, 0.0);
    hs[p * 520 + h1] = (float)fmax(a1[p] + bb1, 0.0);
  }
  __syncthreads();

  if (t < 112) {
    const int p = t / 7, o = t % 7;
    double acc = (double)b2[o];
    for (int h4 = 0; h4 < 128; ++h4) {
      float4 hv = *(const float4*)&hs[p * 520 + h4 * 4];
      acc = fma((double)hv.x, (double)w2[(h4 * 4 + 0) * 7 + o], acc);
      acc = fma((double)hv.y, (double)w2[(h4 * 4 + 1) * 7 + o], acc);
      acc = fma((double)hv.z, (double)w2[(h4 * 4 + 2) * 7 + o], acc);
      acc = fma((double)hv.w, (double)w2[(h4 * 4 + 3) * 7 + o], acc);
    }
    lo[p * 8 + o] = acc;
  }
  __syncthreads();

  if (t < 16) {
    const int p = t, gp = pb + t;
    double m = lo[p * 8 + 0];
    #pragma unroll
    for (int o = 1; o < 7; ++o) m = fmax(m, lo[p * 8 + o]);
    double e[7]; double ssum = 0.0;
    #pragma unroll
    for (int o = 0; o < 7; ++o) { e[o] = exp(lo[p * 8 + o] - m); ssum += e[o]; }
    const double inv = 1.0 / ssum;
    #pragma unroll
    for (int o = 0; o < 7; ++o) {
      double a = e[o] * inv;
      sAB[p * 8 + o] = a;
      out[OUT_AB + (size_t)gp * 7 + o] = (float)a;
    }
    int best = 0; double bv = lo[p * 8 + 0];
    #pragma unroll
    for (int k = 1; k < 5; ++k)
      if (lo[p * 8 + k] > bv) { bv = lo[p * 8 + k]; best = k; }
    #pragma unroll
    for (int k = 0; k < 5; ++k) ids_s[p * 5 + k] = cids[(size_t)gp * 5 + k];
    out[OUT_DOM + gp] = (float)ids_s[p * 5 + best];
  }
  __syncthreads();

  {
    const int p = t >> 4, l16 = t & 15;
    const int gp = pb + p, bz = l16 * 14;
    double r[14];
    #pragma unroll
    for (int j = 0; j < 14; ++j) r[j] = 0.0;
    #pragma unroll
    for (int k = 0; k < 5; ++k) {
      const int idk = ids_s[p * 5 + k];
      const double a = sAB[p * 8 + k];
      const float* pr = proto + (size_t)idk * NB + bz;
      #pragma unroll
      for (int j = 0; j < 14; ++j) r[j] = fma(a, (double)pr[j], r[j]);
    }
    #pragma unroll
    for (int j = 0; j < 14; ++j) out[OUT_RE + (size_t)gp * NB + bz + j] = (float)r[j];
  }
}

extern "C" void kernel_launch(void* const* d_in, const int* in_sizes, int n_in,
                              void* d_out, int out_size, void* d_ws, size_t ws_size,
                              hipStream_t stream) {
  (void)in_sizes; (void)n_in; (void)out_size; (void)ws_size;
  const float* feat  = (const float*)d_in[0];
  const float* w1_s  = (const float*)d_in[1];
  const float* b1_s  = (const float*)d_in[2];
  const float* w2_s  = (const float*)d_in[3];
  const float* b2_s  = (const float*)d_in[4];
  const float* w1_a  = (const float*)d_in[5];
  const float* b1_a  = (const float*)d_in[6];
  const float* w2_a  = (const float*)d_in[7];
  const float* b2_a  = (const float*)d_in[8];
  const float* lab   = (const float*)d_in[9];
  const float* proto = (const float*)d_in[10];
  float* out = (float*)d_out;
  char* ws = (char*)d_ws;
  double* wscores = (double*)(ws + WS_SCORES);
  float*  winvl   = (float*)(ws + WS_INVL);
  int*    wids8   = (int*)(ws + WS_IDS8);
  int*    wcids   = (int*)(ws + WS_CIDS);
  char*   wlab    = ws + WS_LAB;

  (void)hipFuncSetAttribute(reinterpret_cast<const void*>(sims_topk_kernel),
                            hipFuncAttributeMaxDynamicSharedMemorySize, 131072);

  labsplit_kernel<<<dim3(NLIB), dim3(64), 0, stream>>>(lab, wlab);
  libnorm_kernel<<<dim3(NLIB), dim3(64), 0, stream>>>(lab, winvl);
  score_mlp_kernel<<<dim3(P_TOT / 16), dim3(256), 0, stream>>>(
      feat, w1_s, b1_s, w2_s, b2_s, wscores);
  sims_topk_kernel<<<dim3(P_TOT / 64), dim3(512), 131072, stream>>>(
      feat, wlab, winvl, wids8);
  refine_kernel<<<dim3(P_TOT / 4), dim3(256), 0, stream>>>(
      feat, lab, wids8, out, wcids);
  abund_kernel<<<dim3(P_TOT / 16), dim3(256), 0, stream>>>(
      feat, wscores, w1_a, b1_a, w2_a, b2_a, proto, wcids, out);
}

// Round 6
// 1531.053 us; speedup vs baseline: 4.3270x; 1.8666x over previous
//
#include <hip/hip_runtime.h>
#include <math.h>

#define EMB 256
#define HID 512
#define KTOP 5
#define NLIB 16384
#define NB 224
#define P_TOT 32768

/* d_out float layout: [P] dominant | [P][7] abundances | [P][224] recon | [P][5] cand_sims */
#define OUT_DOM ((size_t)0)
#define OUT_AB  ((size_t)P_TOT)
#define OUT_RE  ((size_t)8 * P_TOT)
#define OUT_CS  ((size_t)232 * P_TOT)

/* ws byte layout */
#define WS_SCORES 0                              /* P*5 float  = 655360  */
#define WS_INVL   (P_TOT * KTOP * 4)             /* NLIB float = 65536   */
#define WS_IDS8   (WS_INVL + NLIB * 4)           /* P*8 int    = 1048576 */
#define WS_CIDS   (WS_IDS8 + P_TOT * 8 * 4)      /* P*5 int    = 655360  */
#define WS_LAB    (WS_CIDS + P_TOT * 5 * 4)      /* 1024 chunks * 16KB = 16 MB */

typedef __attribute__((ext_vector_type(8))) short short8;
typedef __attribute__((ext_vector_type(4))) float f32x4;
typedef __attribute__((ext_vector_type(16))) float f32x16;

__device__ __forceinline__ unsigned short f2bf(float x) {
  unsigned int u = __float_as_uint(x);
  u += 0x7fffu + ((u >> 16) & 1u);     /* RNE */
  return (unsigned short)(u >> 16);
}
__device__ __forceinline__ float bf2f(unsigned short b) {
  return __uint_as_float(((unsigned int)b) << 16);
}

__device__ __forceinline__ bool better_(float v, int vi, float e, int ei) {
  return (v > e) || ((v == e) && (vi < ei));  /* jax top_k tie-break: lower id first */
}
__device__ __forceinline__ bool betterd_(double v, int vi, double e, int ei) {
  return (v > e) || ((v == e) && (vi < ei));
}

__device__ __forceinline__ void ins5_(float& s0, int& d0, float& s1, int& d1,
                                      float& s2, int& d2, float& s3, int& d3,
                                      float& s4, int& d4, float v, int vi) {
  if (!better_(v, vi, s4, d4)) return;
  s4 = v; d4 = vi;
  if (better_(s4, d4, s3, d3)) {
    float tf = s3; int td = d3; s3 = s4; d3 = d4; s4 = tf; d4 = td;
    if (better_(s3, d3, s2, d2)) {
      tf = s2; td = d2; s2 = s3; d2 = d3; s3 = tf; d3 = td;
      if (better_(s2, d2, s1, d1)) {
        tf = s1; td = d1; s1 = s2; d1 = d2; s2 = tf; d2 = td;
        if (better_(s1, d1, s0, d0)) {
          tf = s0; td = d0; s0 = s1; d0 = d1; s1 = tf; d1 = td;
        }
      }
    }
  }
}

__device__ __forceinline__ void ins8_(float m[8], int n[8], float v, int vi) {
  if (!better_(v, vi, m[7], n[7])) return;
  m[7] = v; n[7] = vi;
  #pragma unroll
  for (int q = 7; q >= 1; --q) {
    if (better_(m[q], n[q], m[q - 1], n[q - 1])) {
      float tf = m[q - 1]; m[q - 1] = m[q]; m[q] = tf;
      int td = n[q - 1]; n[q - 1] = n[q]; n[q] = td;
    }
  }
}

/* ---------------- kernel 0: lab -> bf16 hi/lo chunk images ----------------
 * chunk c = (row>>8)*16 + k16: [hi 256 rows x 32B][lo 256 rows x 32B] = 16 KB, linear. */
__global__ __launch_bounds__(64) void labsplit_kernel(const float* __restrict__ lab,
                                                      char* __restrict__ wslab) {
  const int row = blockIdx.x;
  const int lane = threadIdx.x;
  const int k16 = lane >> 2, sub = lane & 3;
  float4 v = *(const float4*)(lab + (size_t)row * EMB + k16 * 16 + sub * 4);
  ushort4 ph, pl;
  ph.x = f2bf(v.x); pl.x = f2bf(v.x - bf2f(ph.x));
  ph.y = f2bf(v.y); pl.y = f2bf(v.y - bf2f(ph.y));
  ph.z = f2bf(v.z); pl.z = f2bf(v.z - bf2f(ph.z));
  ph.w = f2bf(v.w); pl.w = f2bf(v.w - bf2f(ph.w));
  const size_t cbase = (size_t)((row >> 8) * 16 + k16) * 16384;
  const size_t off = cbase + (size_t)(row & 255) * 32 + sub * 8;
  *(ushort4*)(wslab + off) = ph;
  *(ushort4*)(wslab + off + 8192) = pl;
}

/* ---------------- kernel 1: library row inverse norms ---------------- */
__global__ __launch_bounds__(64) void libnorm_kernel(const float* __restrict__ lab,
                                                     float* __restrict__ invl) {
  const int row = blockIdx.x;
  const int lane = threadIdx.x;
  float4 v = *(const float4*)(lab + (size_t)row * EMB + lane * 4);
  float s = v.x * v.x + v.y * v.y + v.z * v.z + v.w * v.w;
  #pragma unroll
  for (int off = 32; off >= 1; off >>= 1) s += __shfl_down(s, off);
  if (lane == 0) invl[row] = 1.0f / (sqrtf(s) + 1e-12f);
}

/* ------------- kernel 2: score MLP (256->512->5), f32 ------------- */
__global__ __launch_bounds__(256) void score_mlp_kernel(
    const float* __restrict__ feat, const float* __restrict__ w1,
    const float* __restrict__ b1, const float* __restrict__ w2,
    const float* __restrict__ b2, float* __restrict__ scores) {
  __shared__ __align__(16) float xs[16 * 264];
  __shared__ __align__(16) float hs[16 * 516];
  const int t = threadIdx.x;
  const int pb = blockIdx.x * 16;

  #pragma unroll
  for (int i = 0; i < 4; ++i) {
    int F = i * 256 + t;
    int p = F >> 6, q = (F & 63) * 4;
    *(float4*)&xs[p * 264 + q] = *(const float4*)(feat + (size_t)(pb + p) * EMB + q);
  }
  __syncthreads();

  const int h0 = t, h1 = t + 256;
  float a0[16], a1[16];
  #pragma unroll
  for (int p = 0; p < 16; ++p) { a0[p] = 0.f; a1[p] = 0.f; }

  for (int i4 = 0; i4 < 64; ++i4) {
    const int i = i4 * 4;
    float w00 = w1[(i + 0) * HID + h0], w01 = w1[(i + 1) * HID + h0];
    float w02 = w1[(i + 2) * HID + h0], w03 = w1[(i + 3) * HID + h0];
    float w10 = w1[(i + 0) * HID + h1], w11 = w1[(i + 1) * HID + h1];
    float w12 = w1[(i + 2) * HID + h1], w13 = w1[(i + 3) * HID + h1];
    #pragma unroll
    for (int p = 0; p < 16; ++p) {
      float4 x = *(const float4*)&xs[p * 264 + i];
      a0[p] = fmaf(x.x, w00, a0[p]); a0[p] = fmaf(x.y, w01, a0[p]);
      a0[p] = fmaf(x.z, w02, a0[p]); a0[p] = fmaf(x.w, w03, a0[p]);
      a1[p] = fmaf(x.x, w10, a1[p]); a1[p] = fmaf(x.y, w11, a1[p]);
      a1[p] = fmaf(x.z, w12, a1[p]); a1[p] = fmaf(x.w, w13, a1[p]);
    }
  }
  const float bb0 = b1[h0], bb1 = b1[h1];
  #pragma unroll
  for (int p = 0; p < 16; ++p) {
    hs[p * 516 + h0] = fmaxf(a0[p] + bb0, 0.f);
    hs[p * 516 + h1] = fmaxf(a1[p] + bb1, 0.f);
  }
  __syncthreads();

  if (t < 80) {
    const int p = t / 5, o = t % 5;
    float acc = b2[o];
    for (int h4 = 0; h4 < 128; ++h4) {
      float4 hv = *(const float4*)&hs[p * 516 + h4 * 4];
      acc = fmaf(hv.x, w2[(h4 * 4 + 0) * 5 + o], acc);
      acc = fmaf(hv.y, w2[(h4 * 4 + 1) * 5 + o], acc);
      acc = fmaf(hv.z, w2[(h4 * 4 + 2) * 5 + o], acc);
      acc = fmaf(hv.w, w2[(h4 * 4 + 3) * 5 + o], acc);
    }
    scores[(size_t)(pb + p) * 5 + o] = acc;
  }
}

/* ------------- kernel 3: 32x32x16 bf16x3-split MFMA sims + reg top-5 -> top-8 -------------
 * Block: 128 px, full NLIB sweep; 8 waves = 4 lib-quarters x 2 px-halves; wave tile 64x64.
 * Chunk = 256 libs x 16 k (16 KB image), dbuf via global_load_lds, 1 barrier/iter.
 * C 32x32: col=lane&31 (px), row=(reg&3)+8*(reg>>2)+4*(lane>>5) (lib).
 * LDS 160KB: fhi 64K | flo 64K | lab0 16K | lab1 16K. Feat slot' = slot^(px&31). */
__global__ __launch_bounds__(512, 1) void sims_topk_kernel(
    const float* __restrict__ feat, const char* __restrict__ wslab,
    const float* __restrict__ invl, int* __restrict__ ids8) {
  extern __shared__ char smem[];
  char* fhi = smem;
  char* flo = smem + 65536;
  char* lb0 = smem + 131072;
  char* lb1 = smem + 147456;
  const int t = threadIdx.x;
  const int l = t & 63, w = t >> 6;
  const int q = w & 3, h = w >> 2;
  const int pb = blockIdx.x * 128;

  /* ---- stage features in LDS (one-time): f32 -> bf16 hi/lo, swizzled slots ---- */
  {
    const int px = t >> 2, q4 = t & 3;
    const int pxs = px & 31;
    const float* src = feat + (size_t)(pb + px) * EMB + q4 * 64;
    #pragma unroll
    for (int j = 0; j < 8; ++j) {
      const int slot = q4 * 8 + j;
      float4 v0 = *(const float4*)(src + j * 8);
      float4 v1 = *(const float4*)(src + j * 8 + 4);
      float vv[8] = {v0.x, v0.y, v0.z, v0.w, v1.x, v1.y, v1.z, v1.w};
      unsigned int ph[4], pl[4];
      #pragma unroll
      for (int e = 0; e < 4; ++e) {
        unsigned short ha = f2bf(vv[2 * e]), hb = f2bf(vv[2 * e + 1]);
        unsigned short la = f2bf(vv[2 * e] - bf2f(ha));
        unsigned short lb = f2bf(vv[2 * e + 1] - bf2f(hb));
        ph[e] = (unsigned int)ha | ((unsigned int)hb << 16);
        pl[e] = (unsigned int)la | ((unsigned int)lb << 16);
      }
      const int off = px * 512 + (slot ^ pxs) * 16;
      *(uint4*)(fhi + off) = make_uint4(ph[0], ph[1], ph[2], ph[3]);
      *(uint4*)(flo + off) = make_uint4(pl[0], pl[1], pl[2], pl[3]);
    }
  }

  /* prologue: async-stage chunk 0 -> lb0 (8 waves x 2 x 1KB, linear) */
  #pragma unroll
  for (int j = 0; j < 2; ++j) {
    const int off = (j * 8 + w) * 1024;
    __builtin_amdgcn_global_load_lds(
        (const __attribute__((address_space(1))) unsigned int*)(wslab + off + l * 16),
        (__attribute__((address_space(3))) unsigned int*)(lb0 + off), 16, 0, 0);
  }

  f32x16 acc[2][2];
  #pragma unroll
  for (int mi = 0; mi < 2; ++mi)
    #pragma unroll
    for (int nj = 0; nj < 2; ++nj)
      #pragma unroll
      for (int r = 0; r < 16; ++r) acc[mi][nj][r] = 0.f;

  float ts[2][5]; int ti[2][5];
  #pragma unroll
  for (int nj = 0; nj < 2; ++nj)
    #pragma unroll
    for (int e = 0; e < 5; ++e) { ts[nj][e] = -3.0e38f; ti[nj][e] = 0x7fffffff; }

  __syncthreads();   /* feat ds_writes + chunk0 visible */

  for (int it = 0; it < 1024; ++it) {
    const char* cur = (it & 1) ? lb1 : lb0;
    char* nxt = (it & 1) ? lb0 : lb1;

    if (it + 1 < 1024) {   /* async prefetch next chunk; lands at end-of-iter barrier */
      const char* g = wslab + (size_t)(it + 1) * 16384;
      #pragma unroll
      for (int j = 0; j < 2; ++j) {
        const int off = (j * 8 + w) * 1024;
        __builtin_amdgcn_global_load_lds(
            (const __attribute__((address_space(1))) unsigned int*)(g + off + l * 16),
            (__attribute__((address_space(3))) unsigned int*)(nxt + off), 16, 0, 0);
      }
    }

    /* A frags: rows q*64 + mi*32 + (l&31), k-half l>>5 (linear image, conflict-free) */
    short8 ah[2], al[2];
    #pragma unroll
    for (int mi = 0; mi < 2; ++mi) {
      const int off = (q * 64 + mi * 32 + (l & 31)) * 32 + (l >> 5) * 16;
      ah[mi] = *(const short8*)(cur + off);
      al[mi] = *(const short8*)(cur + 8192 + off);
    }
    const int k16 = it & 15;
    #pragma unroll
    for (int nj = 0; nj < 2; ++nj) {
      const int px = h * 64 + nj * 32 + (l & 31);
      const int boff = px * 512 + (((k16 * 2 + (l >> 5)) ^ (px & 31)) * 16);
      const short8 bh = *(const short8*)(fhi + boff);
      const short8 bl = *(const short8*)(flo + boff);
      #pragma unroll
      for (int mi = 0; mi < 2; ++mi) {
        acc[mi][nj] = __builtin_amdgcn_mfma_f32_32x32x16_bf16(ah[mi], bh, acc[mi][nj], 0, 0, 0);
        acc[mi][nj] = __builtin_amdgcn_mfma_f32_32x32x16_bf16(ah[mi], bl, acc[mi][nj], 0, 0, 0);
        acc[mi][nj] = __builtin_amdgcn_mfma_f32_32x32x16_bf16(al[mi], bh, acc[mi][nj], 0, 0, 0);
      }
    }

    if (k16 == 15) {   /* 256-lib group K-complete: normalize, insert, reset */
      const int gbase = (it >> 4) * 256 + q * 64;
      #pragma unroll
      for (int mi = 0; mi < 2; ++mi) {
        #pragma unroll
        for (int g4 = 0; g4 < 4; ++g4) {
          const int rbase = gbase + mi * 32 + g4 * 8 + (l >> 5) * 4;
          const f32x4 il = *(const f32x4*)(invl + rbase);
          #pragma unroll
          for (int nj = 0; nj < 2; ++nj) {
            #pragma unroll
            for (int rr = 0; rr < 4; ++rr) {
              const float v = acc[mi][nj][g4 * 4 + rr] * il[rr];
              ins5_(ts[nj][0], ti[nj][0], ts[nj][1], ti[nj][1], ts[nj][2], ti[nj][2],
                    ts[nj][3], ti[nj][3], ts[nj][4], ti[nj][4], v, rbase + rr);
            }
          }
        }
      }
      #pragma unroll
      for (int mi = 0; mi < 2; ++mi)
        #pragma unroll
        for (int nj = 0; nj < 2; ++nj)
          #pragma unroll
          for (int r = 0; r < 16; ++r) acc[mi][nj][r] = 0.f;
    }
    __syncthreads();   /* next chunk landed; cur free for overwrite */
  }

  /* ---- final merge: per px 8 lists x 5 -> top-8 ---- */
  float* simsL = (float*)smem;                       /* [128][41] */
  int* idsL = (int*)(smem + 128 * 41 * 4);           /* [128][41] */
  #pragma unroll
  for (int nj = 0; nj < 2; ++nj) {
    const int px = h * 64 + nj * 32 + (l & 31);
    const int col = (q * 2 + (l >> 5)) * 5;
    #pragma unroll
    for (int e = 0; e < 5; ++e) {
      simsL[px * 41 + col + e] = ts[nj][e];
      idsL[px * 41 + col + e] = ti[nj][e];
    }
  }
  __syncthreads();

  if (t < 128) {
    float m[8]; int n[8];
    #pragma unroll
    for (int j = 0; j < 8; ++j) { m[j] = -3.0e38f; n[j] = 0x7fffffff; }
    for (int c = 0; c < 40; ++c)
      ins8_(m, n, simsL[t * 41 + c], idsL[t * 41 + c]);
    const int gp = pb + t;
    #pragma unroll
    for (int j = 0; j < 8; ++j) ids8[(size_t)gp * 8 + j] = n[j];
  }
}

/* ------------- kernel 3b: exact f64 refinement of the 8 candidates ------------- */
__global__ __launch_bounds__(256) void refine_kernel(
    const float* __restrict__ feat, const float* __restrict__ lab,
    const int* __restrict__ ids8, float* __restrict__ out,
    int* __restrict__ cids) {
  const int t = threadIdx.x;
  const int lane = t & 63;
  const int p = blockIdx.x * 4 + (t >> 6);

  float4 f = *(const float4*)(feat + (size_t)p * EMB + lane * 4);
  const double fx = f.x, fy = f.y, fz = f.z, fw = f.w;
  double sf = fx * fx + fy * fy + fz * fz + fw * fw;

  int id[8];
  #pragma unroll
  for (int j = 0; j < 8; ++j) id[j] = ids8[(size_t)p * 8 + j];

  double dot[8], sl[8];
  #pragma unroll
  for (int j = 0; j < 8; ++j) {
    float4 lv = *(const float4*)(lab + (size_t)id[j] * EMB + lane * 4);
    const double lx = lv.x, ly = lv.y, lz = lv.z, lw = lv.w;
    dot[j] = fma(fx, lx, fma(fy, ly, fma(fz, lz, fw * lw)));
    sl[j]  = fma(lx, lx, fma(ly, ly, fma(lz, lz, lw * lw)));
  }
  #pragma unroll
  for (int off = 32; off >= 1; off >>= 1) {
    sf += __shfl_xor(sf, off);
    #pragma unroll
    for (int j = 0; j < 8; ++j) {
      dot[j] += __shfl_xor(dot[j], off);
      sl[j]  += __shfl_xor(sl[j], off);
    }
  }
  if (lane == 0) {
    const double invf = 1.0 / (sqrt(sf) + 1e-12);
    double s[8];
    #pragma unroll
    for (int j = 0; j < 8; ++j)
      s[j] = dot[j] * (1.0 / (sqrt(sl[j]) + 1e-12)) * invf;
    #pragma unroll
    for (int pass = 0; pass < 7; ++pass) {
      #pragma unroll
      for (int i = 0; i < 7; ++i) {
        if (i < 7 - pass) {
          if (betterd_(s[i + 1], id[i + 1], s[i], id[i])) {
            double tv = s[i]; s[i] = s[i + 1]; s[i + 1] = tv;
            int td = id[i]; id[i] = id[i + 1]; id[i + 1] = td;
          }
        }
      }
    }
    #pragma unroll
    for (int k = 0; k < 5; ++k) {
      out[OUT_CS + (size_t)p * 5 + k] = (float)s[k];
      cids[(size_t)p * 5 + k] = id[k];
    }
  }
}

/* ------------- kernel 4: abundance MLP (f32) + softmax + recon + dominant ------------- */
__global__ __launch_bounds__(256) void abund_kernel(
    const float* __restrict__ feat, const float* __restrict__ scores,
    const float* __restrict__ w1, const float* __restrict__ b1,
    const float* __restrict__ w2, const float* __restrict__ b2,
    const float* __restrict__ proto, const int* __restrict__ cids,
    float* __restrict__ out) {
  __shared__ __align__(16) float xs[16 * 264];
  __shared__ __align__(16) float hs[16 * 520];
  __shared__ float scs[16 * 5];
  __shared__ float lo[16 * 8];
  __shared__ float sAB[16 * 8];
  __shared__ int ids_s[16 * 5];
  const int t = threadIdx.x;
  const int pb = blockIdx.x * 16;

  #pragma unroll
  for (int i = 0; i < 4; ++i) {
    int F = i * 256 + t;
    int p = F >> 6, q = (F & 63) * 4;
    *(float4*)&xs[p * 264 + q] = *(const float4*)(feat + (size_t)(pb + p) * EMB + q);
  }
  if (t < 80) scs[t] = scores[(size_t)(pb + t / 5) * 5 + (t % 5)];
  __syncthreads();

  const int h0 = t, h1 = t + 256;
  float a0[16], a1[16];
  #pragma unroll
  for (int p = 0; p < 16; ++p) { a0[p] = 0.f; a1[p] = 0.f; }

  for (int i4 = 0; i4 < 64; ++i4) {
    const int i = i4 * 4;
    float w00 = w1[(i + 0) * HID + h0], w01 = w1[(i + 1) * HID + h0];
    float w02 = w1[(i + 2) * HID + h0], w03 = w1[(i + 3) * HID + h0];
    float w10 = w1[(i + 0) * HID + h1], w11 = w1[(i + 1) * HID + h1];
    float w12 = w1[(i + 2) * HID + h1], w13 = w1[(i + 3) * HID + h1];
    #pragma unroll
    for (int p = 0; p < 16; ++p) {
      float4 x = *(const float4*)&xs[p * 264 + i];
      a0[p] = fmaf(x.x, w00, a0[p]); a0[p] = fmaf(x.y, w01, a0[p]);
      a0[p] = fmaf(x.z, w02, a0[p]); a0[p] = fmaf(x.w, w03, a0[p]);
      a1[p] = fmaf(x.x, w10, a1[p]); a1[p] = fmaf(x.y, w11, a1[p]);
      a1[p] = fmaf(x.z, w12, a1[p]); a1[p] = fmaf(x.w, w13, a1[p]);
    }
  }
  #pragma unroll
  for (int r = 0; r < 5; ++r) {
    float wA = w1[(256 + r) * HID + h0], wB = w1[(256 + r) * HID + h1];
    #pragma unroll
    for (int p = 0; p < 16; ++p) {
      float x = scs[p * 5 + r];
      a0[p] = fmaf(x, wA, a0[p]);
      a1[p] = fmaf(x, wB, a1[p]);
    }
  }
  const float bb0 = b1[h0], bb1 = b1[h1];
  #pragma unroll
  for (int p = 0; p < 16; ++p) {
    hs[p * 520 + h0] = fmaxf(a0[p] + bb0, 0.f);
    hs[p * 520 + h1] = fmaxf(a1[p] + bb1, 0.f);
  }
  __syncthreads();

  if (t < 112) {
    const int p = t / 7, o = t % 7;
    float acc = b2[o];
    for (int h4 = 0; h4 < 128; ++h4) {
      float4 hv = *(const float4*)&hs[p * 520 + h4 * 4];
      acc = fmaf(hv.x, w2[(h4 * 4 + 0) * 7 + o], acc);
      acc = fmaf(hv.y, w2[(h4 * 4 + 1) * 7 + o], acc);
      acc = fmaf(hv.z, w2[(h4 * 4 + 2) * 7 + o], acc);
      acc = fmaf(hv.w, w2[(h4 * 4 + 3) * 7 + o], acc);
    }
    lo[p * 8 + o] = acc;
  }
  __syncthreads();

  if (t < 16) {
    const int p = t, gp = pb + t;
    float m = lo[p * 8 + 0];
    #pragma unroll
    for (int o = 1; o < 7; ++o) m = fmaxf(m, lo[p * 8 + o]);
    float e[7]; float ssum = 0.f;
    #pragma unroll
    for (int o = 0; o < 7; ++o) { e[o] = expf(lo[p * 8 + o] - m); ssum += e[o]; }
    const float inv = 1.0f / ssum;
    #pragma unroll
    for (int o = 0; o < 7; ++o) {
      float a = e[o] * inv;
      sAB[p * 8 + o] = a;
      out[OUT_AB + (size_t)gp * 7 + o] = a;
    }
    /* dominant: argmax over logits[:5] (softmax monotone) */
    int best = 0; float bv = lo[p * 8 + 0];
    #pragma unroll
    for (int k = 1; k < 5; ++k)
      if (lo[p * 8 + k] > bv) { bv = lo[p * 8 + k]; best = k; }
    #pragma unroll
    for (int k = 0; k < 5; ++k) ids_s[p * 5 + k] = cids[(size_t)gp * 5 + k];
    out[OUT_DOM + gp] = (float)ids_s[p * 5 + best];
  }
  __syncthreads();

  {
    const int p = t >> 4, l16 = t & 15;
    const int gp = pb + p, bz = l16 * 14;
    float r[14];
    #pragma unroll
    for (int j = 0; j < 14; ++j) r[j] = 0.f;
    #pragma unroll
    for (int k = 0; k < 5; ++k) {
      const int idk = ids_s[p * 5 + k];
      const float a = sAB[p * 8 + k];
      const float* pr = proto + (size_t)idk * NB + bz;
      #pragma unroll
      for (int j = 0; j < 14; ++j) r[j] = fmaf(a, pr[j], r[j]);
    }
    #pragma unroll
    for (int j = 0; j < 14; ++j) out[OUT_RE + (size_t)gp * NB + bz + j] = r[j];
  }
}

extern "C" void kernel_launch(void* const* d_in, const int* in_sizes, int n_in,
                              void* d_out, int out_size, void* d_ws, size_t ws_size,
                              hipStream_t stream) {
  (void)in_sizes; (void)n_in; (void)out_size; (void)ws_size;
  const float* feat  = (const float*)d_in[0];
  const float* w1_s  = (const float*)d_in[1];
  const float* b1_s  = (const float*)d_in[2];
  const float* w2_s  = (const float*)d_in[3];
  const float* b2_s  = (const float*)d_in[4];
  const float* w1_a  = (const float*)d_in[5];
  const float* b1_a  = (const float*)d_in[6];
  const float* w2_a  = (const float*)d_in[7];
  const float* b2_a  = (const float*)d_in[8];
  const float* lab   = (const float*)d_in[9];
  const float* proto = (const float*)d_in[10];
  float* out = (float*)d_out;
  char* ws = (char*)d_ws;
  float* wscores = (float*)(ws + WS_SCORES);
  float* winvl   = (float*)(ws + WS_INVL);
  int*   wids8   = (int*)(ws + WS_IDS8);
  int*   wcids   = (int*)(ws + WS_CIDS);
  char*  wlab    = ws + WS_LAB;

  (void)hipFuncSetAttribute(reinterpret_cast<const void*>(sims_topk_kernel),
                            hipFuncAttributeMaxDynamicSharedMemorySize, 163840);

  labsplit_kernel<<<dim3(NLIB), dim3(64), 0, stream>>>(lab, wlab);
  libnorm_kernel<<<dim3(NLIB), dim3(64), 0, stream>>>(lab, winvl);
  score_mlp_kernel<<<dim3(P_TOT / 16), dim3(256), 0, stream>>>(
      feat, w1_s, b1_s, w2_s, b2_s, wscores);
  sims_topk_kernel<<<dim3(P_TOT / 128), dim3(512), 163840, stream>>>(
      feat, wlab, winvl, wids8);
  refine_kernel<<<dim3(P_TOT / 4), dim3(256), 0, stream>>>(
      feat, lab, wids8, out, wcids);
  abund_kernel<<<dim3(P_TOT / 16), dim3(256), 0, stream>>>(
      feat, wscores, w1_a, b1_a, w2_a, b2_a, proto, wcids, out);
}

// Round 7
// 1359.426 us; speedup vs baseline: 4.8733x; 1.1262x over previous
//
#include <hip/hip_runtime.h>
#include <math.h>

#define EMB 256
#define HID 512
#define KTOP 5
#define NLIB 16384
#define NB 224
#define P_TOT 32768

/* d_out float layout: [P] dominant | [P][7] abundances | [P][224] recon | [P][5] cand_sims */
#define OUT_DOM ((size_t)0)
#define OUT_AB  ((size_t)P_TOT)
#define OUT_RE  ((size_t)8 * P_TOT)
#define OUT_CS  ((size_t)232 * P_TOT)

/* ws byte layout */
#define WS_SCORES 0                              /* P*5 float  = 655360  */
#define WS_INVL   (P_TOT * KTOP * 4)             /* NLIB float = 65536   */
#define WS_IDS8   (WS_INVL + NLIB * 4)           /* P*8 int    = 1048576 */
#define WS_CIDS   (WS_IDS8 + P_TOT * 8 * 4)      /* P*5 int    = 655360  */
#define WS_LAB    (WS_CIDS + P_TOT * 5 * 4)      /* hi 8MB + lo 8MB lab images */
#define LABLO_OFF ((size_t)NLIB * 32 * 16)       /* 8388608 */

typedef __attribute__((ext_vector_type(8))) short short8;
typedef __attribute__((ext_vector_type(4))) float f32x4;
typedef __attribute__((ext_vector_type(16))) float f32x16;

__device__ __forceinline__ unsigned short f2bf(float x) {
  unsigned int u = __float_as_uint(x);
  u += 0x7fffu + ((u >> 16) & 1u);     /* RNE */
  return (unsigned short)(u >> 16);
}
__device__ __forceinline__ float bf2f(unsigned short b) {
  return __uint_as_float(((unsigned int)b) << 16);
}

__device__ __forceinline__ bool better_(float v, int vi, float e, int ei) {
  return (v > e) || ((v == e) && (vi < ei));  /* jax top_k tie-break: lower id first */
}
__device__ __forceinline__ bool betterd_(double v, int vi, double e, int ei) {
  return (v > e) || ((v == e) && (vi < ei));
}

__device__ __forceinline__ void ins5_(float& s0, int& d0, float& s1, int& d1,
                                      float& s2, int& d2, float& s3, int& d3,
                                      float& s4, int& d4, float v, int vi) {
  if (!better_(v, vi, s4, d4)) return;
  s4 = v; d4 = vi;
  if (better_(s4, d4, s3, d3)) {
    float tf = s3; int td = d3; s3 = s4; d3 = d4; s4 = tf; d4 = td;
    if (better_(s3, d3, s2, d2)) {
      tf = s2; td = d2; s2 = s3; d2 = d3; s3 = tf; d3 = td;
      if (better_(s2, d2, s1, d1)) {
        tf = s1; td = d1; s1 = s2; d1 = d2; s2 = tf; d2 = td;
        if (better_(s1, d1, s0, d0)) {
          tf = s0; td = d0; s0 = s1; d0 = d1; s1 = tf; d1 = td;
        }
      }
    }
  }
}

__device__ __forceinline__ void ins8_(float m[8], int n[8], float v, int vi) {
  if (!better_(v, vi, m[7], n[7])) return;
  m[7] = v; n[7] = vi;
  #pragma unroll
  for (int q = 7; q >= 1; --q) {
    if (better_(m[q], n[q], m[q - 1], n[q - 1])) {
      float tf = m[q - 1]; m[q - 1] = m[q]; m[q] = tf;
      int td = n[q - 1]; n[q - 1] = n[q]; n[q] = td;
    }
  }
}

/* ---------------- kernel 0: lab -> bf16 hi/lo per-k16-plane images ----------------
 * hi byte addr = k16*(NLIB*32) + row*32 + khalf*16 + b8 ; lo at +LABLO_OFF.
 * A wave frag read (rows r0+(l&31), khalf=l>>5) is then a contiguous 1 KB segment. */
__global__ __launch_bounds__(64) void labsplit_kernel(const float* __restrict__ lab,
                                                      char* __restrict__ wslab) {
  const int row = blockIdx.x;
  const int lane = threadIdx.x;        /* k = lane*4 .. lane*4+3 */
  float4 v = *(const float4*)(lab + (size_t)row * EMB + lane * 4);
  ushort4 ph, pl;
  ph.x = f2bf(v.x); pl.x = f2bf(v.x - bf2f(ph.x));
  ph.y = f2bf(v.y); pl.y = f2bf(v.y - bf2f(ph.y));
  ph.z = f2bf(v.z); pl.z = f2bf(v.z - bf2f(ph.z));
  ph.w = f2bf(v.w); pl.w = f2bf(v.w - bf2f(ph.w));
  const int k16 = lane >> 2;
  const int khalf = (lane >> 1) & 1;
  const int b8 = (lane & 1) * 8;
  const size_t off = (size_t)k16 * (NLIB * 32) + (size_t)row * 32 + khalf * 16 + b8;
  *(ushort4*)(wslab + off) = ph;
  *(ushort4*)(wslab + LABLO_OFF + off) = pl;
}

/* ---------------- kernel 1: library row inverse norms ---------------- */
__global__ __launch_bounds__(64) void libnorm_kernel(const float* __restrict__ lab,
                                                     float* __restrict__ invl) {
  const int row = blockIdx.x;
  const int lane = threadIdx.x;
  float4 v = *(const float4*)(lab + (size_t)row * EMB + lane * 4);
  float s = v.x * v.x + v.y * v.y + v.z * v.z + v.w * v.w;
  #pragma unroll
  for (int off = 32; off >= 1; off >>= 1) s += __shfl_down(s, off);
  if (lane == 0) invl[row] = 1.0f / (sqrtf(s) + 1e-12f);
}

/* ------------- kernel 2: score MLP (256->512->5), f32 ------------- */
__global__ __launch_bounds__(256) void score_mlp_kernel(
    const float* __restrict__ feat, const float* __restrict__ w1,
    const float* __restrict__ b1, const float* __restrict__ w2,
    const float* __restrict__ b2, float* __restrict__ scores) {
  __shared__ __align__(16) float xs[16 * 264];
  __shared__ __align__(16) float hs[16 * 516];
  const int t = threadIdx.x;
  const int pb = blockIdx.x * 16;

  #pragma unroll
  for (int i = 0; i < 4; ++i) {
    int F = i * 256 + t;
    int p = F >> 6, q = (F & 63) * 4;
    *(float4*)&xs[p * 264 + q] = *(const float4*)(feat + (size_t)(pb + p) * EMB + q);
  }
  __syncthreads();

  const int h0 = t, h1 = t + 256;
  float a0[16], a1[16];
  #pragma unroll
  for (int p = 0; p < 16; ++p) { a0[p] = 0.f; a1[p] = 0.f; }

  for (int i4 = 0; i4 < 64; ++i4) {
    const int i = i4 * 4;
    float w00 = w1[(i + 0) * HID + h0], w01 = w1[(i + 1) * HID + h0];
    float w02 = w1[(i + 2) * HID + h0], w03 = w1[(i + 3) * HID + h0];
    float w10 = w1[(i + 0) * HID + h1], w11 = w1[(i + 1) * HID + h1];
    float w12 = w1[(i + 2) * HID + h1], w13 = w1[(i + 3) * HID + h1];
    #pragma unroll
    for (int p = 0; p < 16; ++p) {
      float4 x = *(const float4*)&xs[p * 264 + i];
      a0[p] = fmaf(x.x, w00, a0[p]); a0[p] = fmaf(x.y, w01, a0[p]);
      a0[p] = fmaf(x.z, w02, a0[p]); a0[p] = fmaf(x.w, w03, a0[p]);
      a1[p] = fmaf(x.x, w10, a1[p]); a1[p] = fmaf(x.y, w11, a1[p]);
      a1[p] = fmaf(x.z, w12, a1[p]); a1[p] = fmaf(x.w, w13, a1[p]);
    }
  }
  const float bb0 = b1[h0], bb1 = b1[h1];
  #pragma unroll
  for (int p = 0; p < 16; ++p) {
    hs[p * 516 + h0] = fmaxf(a0[p] + bb0, 0.f);
    hs[p * 516 + h1] = fmaxf(a1[p] + bb1, 0.f);
  }
  __syncthreads();

  if (t < 80) {
    const int p = t / 5, o = t % 5;
    float acc = b2[o];
    for (int h4 = 0; h4 < 128; ++h4) {
      float4 hv = *(const float4*)&hs[p * 516 + h4 * 4];
      acc = fmaf(hv.x, w2[(h4 * 4 + 0) * 5 + o], acc);
      acc = fmaf(hv.y, w2[(h4 * 4 + 1) * 5 + o], acc);
      acc = fmaf(hv.z, w2[(h4 * 4 + 2) * 5 + o], acc);
      acc = fmaf(hv.w, w2[(h4 * 4 + 3) * 5 + o], acc);
    }
    scores[(size_t)(pb + p) * 5 + o] = acc;
  }
}

/* ------------- kernel 3: barrier-free 32x32x16 bf16x3 sims + reg top-5 -> top-8 -------------
 * Block: 128 px; 8 waves = 4 lib-quarters (q) x 2 px-halves (h); wave tile 64 libs x 64 px.
 * A (lab) global->reg, 2-deep ping-pong pipeline, no LDS staging, NO loop barriers.
 * B (feat) LDS-resident hi/lo, slot ^ (px&31) -> conflict-free.
 * C 32x32: col=lane&31 (px), row=(reg&3)+8*(reg>>2)+4*(lane>>5) (lib). */
__global__ __launch_bounds__(512, 1) void sims_topk_kernel(
    const float* __restrict__ feat, const char* __restrict__ wslab,
    const float* __restrict__ invl, int* __restrict__ ids8) {
  extern __shared__ char smem[];
  char* fhi = smem;            /* [128 px][32 slot][16B], slot ^= px&31 */
  char* flo = smem + 65536;
  const int t = threadIdx.x;
  const int l = t & 63, w = t >> 6;
  const int q = w & 3, h = w >> 2;
  const int pb = blockIdx.x * 128;

  /* ---- stage features (one-time): f32 -> bf16 hi/lo; slot = j*4+q4 (conflict-light) ---- */
  {
    const int px = t >> 2, q4 = t & 3;
    const int pxs = px & 31;
    const float* src = feat + (size_t)(pb + px) * EMB;
    #pragma unroll
    for (int j = 0; j < 8; ++j) {
      const int slot = j * 4 + q4;
      float4 v0 = *(const float4*)(src + slot * 8);
      float4 v1 = *(const float4*)(src + slot * 8 + 4);
      float vv[8] = {v0.x, v0.y, v0.z, v0.w, v1.x, v1.y, v1.z, v1.w};
      unsigned int ph[4], pl[4];
      #pragma unroll
      for (int e = 0; e < 4; ++e) {
        unsigned short ha = f2bf(vv[2 * e]), hb = f2bf(vv[2 * e + 1]);
        unsigned short la = f2bf(vv[2 * e] - bf2f(ha));
        unsigned short lb = f2bf(vv[2 * e + 1] - bf2f(hb));
        ph[e] = (unsigned int)ha | ((unsigned int)hb << 16);
        pl[e] = (unsigned int)la | ((unsigned int)lb << 16);
      }
      const int off = px * 512 + (slot ^ pxs) * 16;
      *(uint4*)(fhi + off) = make_uint4(ph[0], ph[1], ph[2], ph[3]);
      *(uint4*)(flo + off) = make_uint4(pl[0], pl[1], pl[2], pl[3]);
    }
  }

  f32x16 acc[2][2];
  #pragma unroll
  for (int mi = 0; mi < 2; ++mi)
    #pragma unroll
    for (int nj = 0; nj < 2; ++nj)
      #pragma unroll
      for (int r = 0; r < 16; ++r) acc[mi][nj][r] = 0.f;

  float ts[2][5]; int ti[2][5];
  #pragma unroll
  for (int nj = 0; nj < 2; ++nj)
    #pragma unroll
    for (int e = 0; e < 5; ++e) { ts[nj][e] = -3.0e38f; ti[nj][e] = 0x7fffffff; }

  /* lane-invariant pieces */
  const size_t laneoff = (size_t)(q * 64 + (l & 31)) * 32 + (l >> 5) * 16;
  const int lk = l >> 5;
  const int pxs = l & 31;
  const int pxb0 = (h * 64 + (l & 31)) * 512;
  const int pxb1 = (h * 64 + 32 + (l & 31)) * 512;

#define LOADA(H0, H1, L0, L1, IT) do {                                        \
    const int k16_ = (IT) & 15, st_ = (IT) >> 4;                              \
    const char* pa_ = wslab + (size_t)k16_ * (NLIB * 32) + (size_t)st_ * 8192 \
                      + laneoff;                                              \
    H0 = *(const short8*)(pa_);                                               \
    H1 = *(const short8*)(pa_ + 1024);                                        \
    L0 = *(const short8*)(pa_ + LABLO_OFF);                                   \
    L1 = *(const short8*)(pa_ + LABLO_OFF + 1024);                            \
  } while (0)

#define BODY(IT, H0, H1, L0, L1) do {                                         \
    const int k16_ = (IT) & 15;                                               \
    const int bswz_ = (((k16_ * 2 + lk) ^ pxs) * 16);                         \
    const short8 bh0 = *(const short8*)(fhi + pxb0 + bswz_);                  \
    const short8 bl0 = *(const short8*)(flo + pxb0 + bswz_);                  \
    const short8 bh1 = *(const short8*)(fhi + pxb1 + bswz_);                  \
    const short8 bl1 = *(const short8*)(flo + pxb1 + bswz_);                  \
    acc[0][0] = __builtin_amdgcn_mfma_f32_32x32x16_bf16(H0, bh0, acc[0][0], 0, 0, 0); \
    acc[0][1] = __builtin_amdgcn_mfma_f32_32x32x16_bf16(H0, bh1, acc[0][1], 0, 0, 0); \
    acc[1][0] = __builtin_amdgcn_mfma_f32_32x32x16_bf16(H1, bh0, acc[1][0], 0, 0, 0); \
    acc[1][1] = __builtin_amdgcn_mfma_f32_32x32x16_bf16(H1, bh1, acc[1][1], 0, 0, 0); \
    acc[0][0] = __builtin_amdgcn_mfma_f32_32x32x16_bf16(H0, bl0, acc[0][0], 0, 0, 0); \
    acc[0][1] = __builtin_amdgcn_mfma_f32_32x32x16_bf16(H0, bl1, acc[0][1], 0, 0, 0); \
    acc[1][0] = __builtin_amdgcn_mfma_f32_32x32x16_bf16(L1, bh0, acc[1][0], 0, 0, 0); \
    acc[1][1] = __builtin_amdgcn_mfma_f32_32x32x16_bf16(L1, bh1, acc[1][1], 0, 0, 0); \
    acc[0][0] = __builtin_amdgcn_mfma_f32_32x32x16_bf16(L0, bh0, acc[0][0], 0, 0, 0); \
    acc[0][1] = __builtin_amdgcn_mfma_f32_32x32x16_bf16(L0, bh1, acc[0][1], 0, 0, 0); \
    acc[1][0] = __builtin_amdgcn_mfma_f32_32x32x16_bf16(H1, bl0, acc[1][0], 0, 0, 0); \
    acc[1][1] = __builtin_amdgcn_mfma_f32_32x32x16_bf16(H1, bl1, acc[1][1], 0, 0, 0); \
    if (k16_ == 15) {                                                         \
      const int gbase_ = ((IT) >> 4) * 256 + q * 64;                          \
      _Pragma("unroll")                                                       \
      for (int mi = 0; mi < 2; ++mi) {                                        \
        _Pragma("unroll")                                                     \
        for (int g4 = 0; g4 < 4; ++g4) {                                      \
          const int rbase_ = gbase_ + mi * 32 + g4 * 8 + lk * 4;              \
          const f32x4 il_ = *(const f32x4*)(invl + rbase_);                   \
          _Pragma("unroll")                                                   \
          for (int nj = 0; nj < 2; ++nj) {                                    \
            _Pragma("unroll")                                                 \
            for (int rr = 0; rr < 4; ++rr) {                                  \
              const float v_ = acc[mi][nj][g4 * 4 + rr] * il_[rr];            \
              ins5_(ts[nj][0], ti[nj][0], ts[nj][1], ti[nj][1], ts[nj][2],    \
                    ti[nj][2], ts[nj][3], ti[nj][3], ts[nj][4], ti[nj][4],    \
                    v_, rbase_ + rr);                                         \
            }                                                                 \
          }                                                                   \
        }                                                                     \
      }                                                                       \
      _Pragma("unroll")                                                       \
      for (int mi = 0; mi < 2; ++mi)                                          \
        _Pragma("unroll")                                                     \
        for (int nj = 0; nj < 2; ++nj)                                        \
          _Pragma("unroll")                                                   \
          for (int r = 0; r < 16; ++r) acc[mi][nj][r] = 0.f;                  \
    }                                                                         \
  } while (0)

  short8 a0h0, a0h1, a0l0, a0l1;   /* ping */
  short8 a1h0, a1h1, a1l0, a1l1;   /* pong */
  LOADA(a0h0, a0h1, a0l0, a0l1, 0);

  __syncthreads();   /* feat LDS ready (only barrier before merge) */

  #pragma unroll 1
  for (int it2 = 0; it2 < 1024; it2 += 2) {
    LOADA(a1h0, a1h1, a1l0, a1l1, it2 + 1);
    BODY(it2, a0h0, a0h1, a0l0, a0l1);
    if (it2 + 2 < 1024) LOADA(a0h0, a0h1, a0l0, a0l1, it2 + 2);
    BODY(it2 + 1, a1h0, a1h1, a1l0, a1l1);
  }
#undef LOADA
#undef BODY

  /* ---- final merge: per px 8 lists x 5 -> top-8 ---- */
  __syncthreads();   /* all waves done reading fhi/flo */
  float* simsL = (float*)smem;                       /* [128][41] */
  int* idsL = (int*)(smem + 128 * 41 * 4);           /* [128][41] */
  #pragma unroll
  for (int nj = 0; nj < 2; ++nj) {
    const int px = h * 64 + nj * 32 + (l & 31);
    const int col = (q * 2 + lk) * 5;
    #pragma unroll
    for (int e = 0; e < 5; ++e) {
      simsL[px * 41 + col + e] = ts[nj][e];
      idsL[px * 41 + col + e] = ti[nj][e];
    }
  }
  __syncthreads();

  if (t < 128) {
    float m[8]; int n[8];
    #pragma unroll
    for (int j = 0; j < 8; ++j) { m[j] = -3.0e38f; n[j] = 0x7fffffff; }
    for (int c = 0; c < 40; ++c)
      ins8_(m, n, simsL[t * 41 + c], idsL[t * 41 + c]);
    const int gp = pb + t;
    #pragma unroll
    for (int j = 0; j < 8; ++j) ids8[(size_t)gp * 8 + j] = n[j];
  }
}

/* ------------- kernel 3b: exact f64 refinement of the 8 candidates ------------- */
__global__ __launch_bounds__(256) void refine_kernel(
    const float* __restrict__ feat, const float* __restrict__ lab,
    const int* __restrict__ ids8, float* __restrict__ out,
    int* __restrict__ cids) {
  const int t = threadIdx.x;
  const int lane = t & 63;
  const int p = blockIdx.x * 4 + (t >> 6);

  float4 f = *(const float4*)(feat + (size_t)p * EMB + lane * 4);
  const double fx = f.x, fy = f.y, fz = f.z, fw = f.w;
  double sf = fx * fx + fy * fy + fz * fz + fw * fw;

  int id[8];
  #pragma unroll
  for (int j = 0; j < 8; ++j) id[j] = ids8[(size_t)p * 8 + j];

  double dot[8], sl[8];
  #pragma unroll
  for (int j = 0; j < 8; ++j) {
    float4 lv = *(const float4*)(lab + (size_t)id[j] * EMB + lane * 4);
    const double lx = lv.x, ly = lv.y, lz = lv.z, lw = lv.w;
    dot[j] = fma(fx, lx, fma(fy, ly, fma(fz, lz, fw * lw)));
    sl[j]  = fma(lx, lx, fma(ly, ly, fma(lz, lz, lw * lw)));
  }
  #pragma unroll
  for (int off = 32; off >= 1; off >>= 1) {
    sf += __shfl_xor(sf, off);
    #pragma unroll
    for (int j = 0; j < 8; ++j) {
      dot[j] += __shfl_xor(dot[j], off);
      sl[j]  += __shfl_xor(sl[j], off);
    }
  }
  if (lane == 0) {
    const double invf = 1.0 / (sqrt(sf) + 1e-12);
    double s[8];
    #pragma unroll
    for (int j = 0; j < 8; ++j)
      s[j] = dot[j] * (1.0 / (sqrt(sl[j]) + 1e-12)) * invf;
    #pragma unroll
    for (int pass = 0; pass < 7; ++pass) {
      #pragma unroll
      for (int i = 0; i < 7; ++i) {
        if (i < 7 - pass) {
          if (betterd_(s[i + 1], id[i + 1], s[i], id[i])) {
            double tv = s[i]; s[i] = s[i + 1]; s[i + 1] = tv;
            int td = id[i]; id[i] = id[i + 1]; id[i + 1] = td;
          }
        }
      }
    }
    #pragma unroll
    for (int k = 0; k < 5; ++k) {
      out[OUT_CS + (size_t)p * 5 + k] = (float)s[k];
      cids[(size_t)p * 5 + k] = id[k];
    }
  }
}

/* ------------- kernel 4: abundance MLP (f32) + softmax + recon + dominant ------------- */
__global__ __launch_bounds__(256) void abund_kernel(
    const float* __restrict__ feat, const float* __restrict__ scores,
    const float* __restrict__ w1, const float* __restrict__ b1,
    const float* __restrict__ w2, const float* __restrict__ b2,
    const float* __restrict__ proto, const int* __restrict__ cids,
    float* __restrict__ out) {
  __shared__ __align__(16) float xs[16 * 264];
  __shared__ __align__(16) float hs[16 * 520];
  __shared__ float scs[16 * 5];
  __shared__ float lo[16 * 8];
  __shared__ float sAB[16 * 8];
  __shared__ int ids_s[16 * 5];
  const int t = threadIdx.x;
  const int pb = blockIdx.x * 16;

  #pragma unroll
  for (int i = 0; i < 4; ++i) {
    int F = i * 256 + t;
    int p = F >> 6, q = (F & 63) * 4;
    *(float4*)&xs[p * 264 + q] = *(const float4*)(feat + (size_t)(pb + p) * EMB + q);
  }
  if (t < 80) scs[t] = scores[(size_t)(pb + t / 5) * 5 + (t % 5)];
  __syncthreads();

  const int h0 = t, h1 = t + 256;
  float a0[16], a1[16];
  #pragma unroll
  for (int p = 0; p < 16; ++p) { a0[p] = 0.f; a1[p] = 0.f; }

  for (int i4 = 0; i4 < 64; ++i4) {
    const int i = i4 * 4;
    float w00 = w1[(i + 0) * HID + h0], w01 = w1[(i + 1) * HID + h0];
    float w02 = w1[(i + 2) * HID + h0], w03 = w1[(i + 3) * HID + h0];
    float w10 = w1[(i + 0) * HID + h1], w11 = w1[(i + 1) * HID + h1];
    float w12 = w1[(i + 2) * HID + h1], w13 = w1[(i + 3) * HID + h1];
    #pragma unroll
    for (int p = 0; p < 16; ++p) {
      float4 x = *(const float4*)&xs[p * 264 + i];
      a0[p] = fmaf(x.x, w00, a0[p]); a0[p] = fmaf(x.y, w01, a0[p]);
      a0[p] = fmaf(x.z, w02, a0[p]); a0[p] = fmaf(x.w, w03, a0[p]);
      a1[p] = fmaf(x.x, w10, a1[p]); a1[p] = fmaf(x.y, w11, a1[p]);
      a1[p] = fmaf(x.z, w12, a1[p]); a1[p] = fmaf(x.w, w13, a1[p]);
    }
  }
  #pragma unroll
  for (int r = 0; r < 5; ++r) {
    float wA = w1[(256 + r) * HID + h0], wB = w1[(256 + r) * HID + h1];
    #pragma unroll
    for (int p = 0; p < 16; ++p) {
      float x = scs[p * 5 + r];
      a0[p] = fmaf(x, wA, a0[p]);
      a1[p] = fmaf(x, wB, a1[p]);
    }
  }
  const float bb0 = b1[h0], bb1 = b1[h1];
  #pragma unroll
  for (int p = 0; p < 16; ++p) {
    hs[p * 520 + h0] = fmaxf(a0[p] + bb0, 0.f);
    hs[p * 520 + h1] = fmaxf(a1[p] + bb1, 0.f);
  }
  __syncthreads();

  if (t < 112) {
    const int p = t / 7, o = t % 7;
    float acc = b2[o];
    for (int h4 = 0; h4 < 128; ++h4) {
      float4 hv = *(const float4*)&hs[p * 520 + h4 * 4];
      acc = fmaf(hv.x, w2[(h4 * 4 + 0) * 7 + o], acc);
      acc = fmaf(hv.y, w2[(h4 * 4 + 1) * 7 + o], acc);
      acc = fmaf(hv.z, w2[(h4 * 4 + 2) * 7 + o], acc);
      acc = fmaf(hv.w, w2[(h4 * 4 + 3) * 7 + o], acc);
    }
    lo[p * 8 + o] = acc;
  }
  __syncthreads();

  if (t < 16) {
    const int p = t, gp = pb + t;
    float m = lo[p * 8 + 0];
    #pragma unroll
    for (int o = 1; o < 7; ++o) m = fmaxf(m, lo[p * 8 + o]);
    float e[7]; float ssum = 0.f;
    #pragma unroll
    for (int o = 0; o < 7; ++o) { e[o] = expf(lo[p * 8 + o] - m); ssum += e[o]; }
    const float inv = 1.0f / ssum;
    #pragma unroll
    for (int o = 0; o < 7; ++o) {
      float a = e[o] * inv;
      sAB[p * 8 + o] = a;
      out[OUT_AB + (size_t)gp * 7 + o] = a;
    }
    /* dominant: argmax over logits[:5] (softmax monotone) */
    int best = 0; float bv = lo[p * 8 + 0];
    #pragma unroll
    for (int k = 1; k < 5; ++k)
      if (lo[p * 8 + k] > bv) { bv = lo[p * 8 + k]; best = k; }
    #pragma unroll
    for (int k = 0; k < 5; ++k) ids_s[p * 5 + k] = cids[(size_t)gp * 5 + k];
    out[OUT_DOM + gp] = (float)ids_s[p * 5 + best];
  }
  __syncthreads();

  {
    const int p = t >> 4, l16 = t & 15;
    const int gp = pb + p, bz = l16 * 14;
    float r[14];
    #pragma unroll
    for (int j = 0; j < 14; ++j) r[j] = 0.f;
    #pragma unroll
    for (int k = 0; k < 5; ++k) {
      const int idk = ids_s[p * 5 + k];
      const float a = sAB[p * 8 + k];
      const float* pr = proto + (size_t)idk * NB + bz;
      #pragma unroll
      for (int j = 0; j < 14; ++j) r[j] = fmaf(a, pr[j], r[j]);
    }
    #pragma unroll
    for (int j = 0; j < 14; ++j) out[OUT_RE + (size_t)gp * NB + bz + j] = r[j];
  }
}

extern "C" void kernel_launch(void* const* d_in, const int* in_sizes, int n_in,
                              void* d_out, int out_size, void* d_ws, size_t ws_size,
                              hipStream_t stream) {
  (void)in_sizes; (void)n_in; (void)out_size; (void)ws_size;
  const float* feat  = (const float*)d_in[0];
  const float* w1_s  = (const float*)d_in[1];
  const float* b1_s  = (const float*)d_in[2];
  const float* w2_s  = (const float*)d_in[3];
  const float* b2_s  = (const float*)d_in[4];
  const float* w1_a  = (const float*)d_in[5];
  const float* b1_a  = (const float*)d_in[6];
  const float* w2_a  = (const float*)d_in[7];
  const float* b2_a  = (const float*)d_in[8];
  const float* lab   = (const float*)d_in[9];
  const float* proto = (const float*)d_in[10];
  float* out = (float*)d_out;
  char* ws = (char*)d_ws;
  float* wscores = (float*)(ws + WS_SCORES);
  float* winvl   = (float*)(ws + WS_INVL);
  int*   wids8   = (int*)(ws + WS_IDS8);
  int*   wcids   = (int*)(ws + WS_CIDS);
  char*  wlab    = ws + WS_LAB;

  (void)hipFuncSetAttribute(reinterpret_cast<const void*>(sims_topk_kernel),
                            hipFuncAttributeMaxDynamicSharedMemorySize, 131072);

  labsplit_kernel<<<dim3(NLIB), dim3(64), 0, stream>>>(lab, wlab);
  libnorm_kernel<<<dim3(NLIB), dim3(64), 0, stream>>>(lab, winvl);
  score_mlp_kernel<<<dim3(P_TOT / 16), dim3(256), 0, stream>>>(
      feat, w1_s, b1_s, w2_s, b2_s, wscores);
  sims_topk_kernel<<<dim3(P_TOT / 128), dim3(512), 131072, stream>>>(
      feat, wlab, winvl, wids8);
  refine_kernel<<<dim3(P_TOT / 4), dim3(256), 0, stream>>>(
      feat, lab, wids8, out, wcids);
  abund_kernel<<<dim3(P_TOT / 16), dim3(256), 0, stream>>>(
      feat, wscores, w1_a, b1_a, w2_a, b2_a, proto, wcids, out);
}

// Round 8
// 1343.541 us; speedup vs baseline: 4.9309x; 1.0118x over previous
//
#include <hip/hip_runtime.h>
#include <math.h>

#define EMB 256
#define HID 512
#define KTOP 5
#define NLIB 16384
#define NB 224
#define P_TOT 32768

/* d_out float layout: [P] dominant | [P][7] abundances | [P][224] recon | [P][5] cand_sims */
#define OUT_DOM ((size_t)0)
#define OUT_AB  ((size_t)P_TOT)
#define OUT_RE  ((size_t)8 * P_TOT)
#define OUT_CS  ((size_t)232 * P_TOT)

/* ws byte layout */
#define WS_SCORES 0                              /* P*5 float  = 655360  */
#define WS_INVL   (P_TOT * KTOP * 4)             /* NLIB float = 65536   */
#define WS_IDS8   (WS_INVL + NLIB * 4)           /* P*8 int    = 1048576 */
#define WS_CIDS   (WS_IDS8 + P_TOT * 8 * 4)      /* P*5 int    = 655360  */
#define WS_LAB    (WS_CIDS + P_TOT * 5 * 4)      /* hi 8MB + lo 8MB lab images */
#define LABLO_OFF ((size_t)NLIB * 32 * 16)       /* 8388608 */

typedef __attribute__((ext_vector_type(8))) short short8;
typedef __attribute__((ext_vector_type(4))) float f32x4;
typedef __attribute__((ext_vector_type(16))) float f32x16;

__device__ __forceinline__ unsigned short f2bf(float x) {
  unsigned int u = __float_as_uint(x);
  u += 0x7fffu + ((u >> 16) & 1u);     /* RNE */
  return (unsigned short)(u >> 16);
}
__device__ __forceinline__ float bf2f(unsigned short b) {
  return __uint_as_float(((unsigned int)b) << 16);
}

__device__ __forceinline__ bool better_(float v, int vi, float e, int ei) {
  return (v > e) || ((v == e) && (vi < ei));  /* jax top_k tie-break: lower id first */
}
__device__ __forceinline__ bool betterd_(double v, int vi, double e, int ei) {
  return (v > e) || ((v == e) && (vi < ei));
}

__device__ __forceinline__ void ins5_(float& s0, int& d0, float& s1, int& d1,
                                      float& s2, int& d2, float& s3, int& d3,
                                      float& s4, int& d4, float v, int vi) {
  if (!better_(v, vi, s4, d4)) return;
  s4 = v; d4 = vi;
  if (better_(s4, d4, s3, d3)) {
    float tf = s3; int td = d3; s3 = s4; d3 = d4; s4 = tf; d4 = td;
    if (better_(s3, d3, s2, d2)) {
      tf = s2; td = d2; s2 = s3; d2 = d3; s3 = tf; d3 = td;
      if (better_(s2, d2, s1, d1)) {
        tf = s1; td = d1; s1 = s2; d1 = d2; s2 = tf; d2 = td;
        if (better_(s1, d1, s0, d0)) {
          tf = s0; td = d0; s0 = s1; d0 = d1; s1 = tf; d1 = td;
        }
      }
    }
  }
}

__device__ __forceinline__ void ins8_(float m[8], int n[8], float v, int vi) {
  if (!better_(v, vi, m[7], n[7])) return;
  m[7] = v; n[7] = vi;
  #pragma unroll
  for (int q = 7; q >= 1; --q) {
    if (better_(m[q], n[q], m[q - 1], n[q - 1])) {
      float tf = m[q - 1]; m[q - 1] = m[q]; m[q] = tf;
      int td = n[q - 1]; n[q - 1] = n[q]; n[q] = td;
    }
  }
}

/* ---------------- kernel 0: lab -> bf16 hi/lo per-k16-plane images ----------------
 * hi byte addr = k16*(NLIB*32) + row*32 + khalf*16 + b8 ; lo at +LABLO_OFF.
 * A wave frag read (rows r0+(l&31), khalf=l>>5) is then a contiguous 1 KB segment. */
__global__ __launch_bounds__(64) void labsplit_kernel(const float* __restrict__ lab,
                                                      char* __restrict__ wslab) {
  const int row = blockIdx.x;
  const int lane = threadIdx.x;        /* k = lane*4 .. lane*4+3 */
  float4 v = *(const float4*)(lab + (size_t)row * EMB + lane * 4);
  ushort4 ph, pl;
  ph.x = f2bf(v.x); pl.x = f2bf(v.x - bf2f(ph.x));
  ph.y = f2bf(v.y); pl.y = f2bf(v.y - bf2f(ph.y));
  ph.z = f2bf(v.z); pl.z = f2bf(v.z - bf2f(ph.z));
  ph.w = f2bf(v.w); pl.w = f2bf(v.w - bf2f(ph.w));
  const int k16 = lane >> 2;
  const int khalf = (lane >> 1) & 1;
  const int b8 = (lane & 1) * 8;
  const size_t off = (size_t)k16 * (NLIB * 32) + (size_t)row * 32 + khalf * 16 + b8;
  *(ushort4*)(wslab + off) = ph;
  *(ushort4*)(wslab + LABLO_OFF + off) = pl;
}

/* ---------------- kernel 1: library row inverse norms ---------------- */
__global__ __launch_bounds__(64) void libnorm_kernel(const float* __restrict__ lab,
                                                     float* __restrict__ invl) {
  const int row = blockIdx.x;
  const int lane = threadIdx.x;
  float4 v = *(const float4*)(lab + (size_t)row * EMB + lane * 4);
  float s = v.x * v.x + v.y * v.y + v.z * v.z + v.w * v.w;
  #pragma unroll
  for (int off = 32; off >= 1; off >>= 1) s += __shfl_down(s, off);
  if (lane == 0) invl[row] = 1.0f / (sqrtf(s) + 1e-12f);
}

/* ------------- kernel 2: score MLP (256->512->5), f32 ------------- */
__global__ __launch_bounds__(256) void score_mlp_kernel(
    const float* __restrict__ feat, const float* __restrict__ w1,
    const float* __restrict__ b1, const float* __restrict__ w2,
    const float* __restrict__ b2, float* __restrict__ scores) {
  __shared__ __align__(16) float xs[16 * 264];
  __shared__ __align__(16) float hs[16 * 516];
  const int t = threadIdx.x;
  const int pb = blockIdx.x * 16;

  #pragma unroll
  for (int i = 0; i < 4; ++i) {
    int F = i * 256 + t;
    int p = F >> 6, q = (F & 63) * 4;
    *(float4*)&xs[p * 264 + q] = *(const float4*)(feat + (size_t)(pb + p) * EMB + q);
  }
  __syncthreads();

  const int h0 = t, h1 = t + 256;
  float a0[16], a1[16];
  #pragma unroll
  for (int p = 0; p < 16; ++p) { a0[p] = 0.f; a1[p] = 0.f; }

  for (int i4 = 0; i4 < 64; ++i4) {
    const int i = i4 * 4;
    float w00 = w1[(i + 0) * HID + h0], w01 = w1[(i + 1) * HID + h0];
    float w02 = w1[(i + 2) * HID + h0], w03 = w1[(i + 3) * HID + h0];
    float w10 = w1[(i + 0) * HID + h1], w11 = w1[(i + 1) * HID + h1];
    float w12 = w1[(i + 2) * HID + h1], w13 = w1[(i + 3) * HID + h1];
    #pragma unroll
    for (int p = 0; p < 16; ++p) {
      float4 x = *(const float4*)&xs[p * 264 + i];
      a0[p] = fmaf(x.x, w00, a0[p]); a0[p] = fmaf(x.y, w01, a0[p]);
      a0[p] = fmaf(x.z, w02, a0[p]); a0[p] = fmaf(x.w, w03, a0[p]);
      a1[p] = fmaf(x.x, w10, a1[p]); a1[p] = fmaf(x.y, w11, a1[p]);
      a1[p] = fmaf(x.z, w12, a1[p]); a1[p] = fmaf(x.w, w13, a1[p]);
    }
  }
  const float bb0 = b1[h0], bb1 = b1[h1];
  #pragma unroll
  for (int p = 0; p < 16; ++p) {
    hs[p * 516 + h0] = fmaxf(a0[p] + bb0, 0.f);
    hs[p * 516 + h1] = fmaxf(a1[p] + bb1, 0.f);
  }
  __syncthreads();

  if (t < 80) {
    const int p = t / 5, o = t % 5;
    float acc = b2[o];
    for (int h4 = 0; h4 < 128; ++h4) {
      float4 hv = *(const float4*)&hs[p * 516 + h4 * 4];
      acc = fmaf(hv.x, w2[(h4 * 4 + 0) * 5 + o], acc);
      acc = fmaf(hv.y, w2[(h4 * 4 + 1) * 5 + o], acc);
      acc = fmaf(hv.z, w2[(h4 * 4 + 2) * 5 + o], acc);
      acc = fmaf(hv.w, w2[(h4 * 4 + 3) * 5 + o], acc);
    }
    scores[(size_t)(pb + p) * 5 + o] = acc;
  }
}

/* ------------- kernel 3: barrier-free 32x32x16 bf16x3 sims, 4-deep A pipeline -------------
 * Block: 128 px; 8 waves = 4 lib-quarters (q) x 2 px-halves (h); wave tile 64 libs x 64 px.
 * A (lab) global->reg, 4-deep named ping-pong (loads issued 3 iters ahead of use),
 * no LDS staging, NO loop barriers. B (feat) LDS-resident hi/lo, slot^(px&31).
 * C 32x32: col=lane&31 (px), row=(reg&3)+8*(reg>>2)+4*(lane>>5) (lib). */
__global__ __launch_bounds__(512, 1) void sims_topk_kernel(
    const float* __restrict__ feat, const char* __restrict__ wslab,
    const float* __restrict__ invl, int* __restrict__ ids8) {
  extern __shared__ char smem[];
  char* fhi = smem;            /* [128 px][32 slot][16B], slot ^= px&31 */
  char* flo = smem + 65536;
  const int t = threadIdx.x;
  const int l = t & 63, w = t >> 6;
  const int q = w & 3, h = w >> 2;
  const int pb = blockIdx.x * 128;

  /* ---- stage features (one-time): f32 -> bf16 hi/lo; slot = j*4+q4 ---- */
  {
    const int px = t >> 2, q4 = t & 3;
    const int pxs = px & 31;
    const float* src = feat + (size_t)(pb + px) * EMB;
    #pragma unroll
    for (int j = 0; j < 8; ++j) {
      const int slot = j * 4 + q4;
      float4 v0 = *(const float4*)(src + slot * 8);
      float4 v1 = *(const float4*)(src + slot * 8 + 4);
      float vv[8] = {v0.x, v0.y, v0.z, v0.w, v1.x, v1.y, v1.z, v1.w};
      unsigned int ph[4], pl[4];
      #pragma unroll
      for (int e = 0; e < 4; ++e) {
        unsigned short ha = f2bf(vv[2 * e]), hb = f2bf(vv[2 * e + 1]);
        unsigned short la = f2bf(vv[2 * e] - bf2f(ha));
        unsigned short lb = f2bf(vv[2 * e + 1] - bf2f(hb));
        ph[e] = (unsigned int)ha | ((unsigned int)hb << 16);
        pl[e] = (unsigned int)la | ((unsigned int)lb << 16);
      }
      const int off = px * 512 + (slot ^ pxs) * 16;
      *(uint4*)(fhi + off) = make_uint4(ph[0], ph[1], ph[2], ph[3]);
      *(uint4*)(flo + off) = make_uint4(pl[0], pl[1], pl[2], pl[3]);
    }
  }

  f32x16 acc[2][2];
  #pragma unroll
  for (int mi = 0; mi < 2; ++mi)
    #pragma unroll
    for (int nj = 0; nj < 2; ++nj)
      #pragma unroll
      for (int r = 0; r < 16; ++r) acc[mi][nj][r] = 0.f;

  float ts[2][5]; int ti[2][5];
  #pragma unroll
  for (int nj = 0; nj < 2; ++nj)
    #pragma unroll
    for (int e = 0; e < 5; ++e) { ts[nj][e] = -3.0e38f; ti[nj][e] = 0x7fffffff; }

  /* lane-invariant pieces */
  const size_t laneoff = (size_t)(q * 64 + (l & 31)) * 32 + (l >> 5) * 16;
  const int lk = l >> 5;
  const int pxs = l & 31;
  const int pxb0 = (h * 64 + (l & 31)) * 512;
  const int pxb1 = (h * 64 + 32 + (l & 31)) * 512;

#define LOADA(H0, H1, L0, L1, IT) do {                                        \
    const int it_ = (IT) < 1024 ? (IT) : 0;                                   \
    const int k16_ = it_ & 15, st_ = it_ >> 4;                                \
    const char* pa_ = wslab + (size_t)k16_ * (NLIB * 32) + (size_t)st_ * 8192 \
                      + laneoff;                                              \
    H0 = *(const short8*)(pa_);                                               \
    H1 = *(const short8*)(pa_ + 1024);                                        \
    L0 = *(const short8*)(pa_ + LABLO_OFF);                                   \
    L1 = *(const short8*)(pa_ + LABLO_OFF + 1024);                            \
  } while (0)

#define BODY(IT, H0, H1, L0, L1) do {                                         \
    const int k16_ = (IT) & 15;                                               \
    const int bswz_ = (((k16_ * 2 + lk) ^ pxs) * 16);                         \
    const short8 bh0 = *(const short8*)(fhi + pxb0 + bswz_);                  \
    const short8 bl0 = *(const short8*)(flo + pxb0 + bswz_);                  \
    const short8 bh1 = *(const short8*)(fhi + pxb1 + bswz_);                  \
    const short8 bl1 = *(const short8*)(flo + pxb1 + bswz_);                  \
    acc[0][0] = __builtin_amdgcn_mfma_f32_32x32x16_bf16(H0, bh0, acc[0][0], 0, 0, 0); \
    acc[0][1] = __builtin_amdgcn_mfma_f32_32x32x16_bf16(H0, bh1, acc[0][1], 0, 0, 0); \
    acc[1][0] = __builtin_amdgcn_mfma_f32_32x32x16_bf16(H1, bh0, acc[1][0], 0, 0, 0); \
    acc[1][1] = __builtin_amdgcn_mfma_f32_32x32x16_bf16(H1, bh1, acc[1][1], 0, 0, 0); \
    acc[0][0] = __builtin_amdgcn_mfma_f32_32x32x16_bf16(H0, bl0, acc[0][0], 0, 0, 0); \
    acc[0][1] = __builtin_amdgcn_mfma_f32_32x32x16_bf16(H0, bl1, acc[0][1], 0, 0, 0); \
    acc[1][0] = __builtin_amdgcn_mfma_f32_32x32x16_bf16(L1, bh0, acc[1][0], 0, 0, 0); \
    acc[1][1] = __builtin_amdgcn_mfma_f32_32x32x16_bf16(L1, bh1, acc[1][1], 0, 0, 0); \
    acc[0][0] = __builtin_amdgcn_mfma_f32_32x32x16_bf16(L0, bh0, acc[0][0], 0, 0, 0); \
    acc[0][1] = __builtin_amdgcn_mfma_f32_32x32x16_bf16(L0, bh1, acc[0][1], 0, 0, 0); \
    acc[1][0] = __builtin_amdgcn_mfma_f32_32x32x16_bf16(H1, bl0, acc[1][0], 0, 0, 0); \
    acc[1][1] = __builtin_amdgcn_mfma_f32_32x32x16_bf16(H1, bl1, acc[1][1], 0, 0, 0); \
    if (k16_ == 15) {                                                         \
      const int gbase_ = ((IT) >> 4) * 256 + q * 64;                          \
      _Pragma("unroll")                                                       \
      for (int mi = 0; mi < 2; ++mi) {                                        \
        _Pragma("unroll")                                                     \
        for (int g4 = 0; g4 < 4; ++g4) {                                      \
          const int rbase_ = gbase_ + mi * 32 + g4 * 8 + lk * 4;              \
          const f32x4 il_ = *(const f32x4*)(invl + rbase_);                   \
          _Pragma("unroll")                                                   \
          for (int nj = 0; nj < 2; ++nj) {                                    \
            _Pragma("unroll")                                                 \
            for (int rr = 0; rr < 4; ++rr) {                                  \
              const float v_ = acc[mi][nj][g4 * 4 + rr] * il_[rr];            \
              ins5_(ts[nj][0], ti[nj][0], ts[nj][1], ti[nj][1], ts[nj][2],    \
                    ti[nj][2], ts[nj][3], ti[nj][3], ts[nj][4], ti[nj][4],    \
                    v_, rbase_ + rr);                                         \
            }                                                                 \
          }                                                                   \
        }                                                                     \
      }                                                                       \
      _Pragma("unroll")                                                       \
      for (int mi = 0; mi < 2; ++mi)                                          \
        _Pragma("unroll")                                                     \
        for (int nj = 0; nj < 2; ++nj)                                        \
          _Pragma("unroll")                                                   \
          for (int r = 0; r < 16; ++r) acc[mi][nj][r] = 0.f;                  \
    }                                                                         \
  } while (0)

  /* 4-deep named ping-pong buffer sets (rule #20: all static indexing) */
  short8 aAh0, aAh1, aAl0, aAl1;
  short8 aBh0, aBh1, aBl0, aBl1;
  short8 aCh0, aCh1, aCl0, aCl1;
  short8 aDh0, aDh1, aDl0, aDl1;
  LOADA(aAh0, aAh1, aAl0, aAl1, 0);
  LOADA(aBh0, aBh1, aBl0, aBl1, 1);
  LOADA(aCh0, aCh1, aCl0, aCl1, 2);

  __syncthreads();   /* feat LDS ready (only barrier before merge) */

  #pragma unroll 1
  for (int it2 = 0; it2 < 1024; it2 += 4) {
    LOADA(aDh0, aDh1, aDl0, aDl1, it2 + 3);
    BODY(it2, aAh0, aAh1, aAl0, aAl1);
    LOADA(aAh0, aAh1, aAl0, aAl1, it2 + 4);
    BODY(it2 + 1, aBh0, aBh1, aBl0, aBl1);
    LOADA(aBh0, aBh1, aBl0, aBl1, it2 + 5);
    BODY(it2 + 2, aCh0, aCh1, aCl0, aCl1);
    LOADA(aCh0, aCh1, aCl0, aCl1, it2 + 6);
    BODY(it2 + 3, aDh0, aDh1, aDl0, aDl1);
  }
#undef LOADA
#undef BODY

  /* ---- final merge: per px 8 lists x 5 -> top-8 ---- */
  __syncthreads();   /* all waves done reading fhi/flo */
  float* simsL = (float*)smem;                       /* [128][41] */
  int* idsL = (int*)(smem + 128 * 41 * 4);           /* [128][41] */
  #pragma unroll
  for (int nj = 0; nj < 2; ++nj) {
    const int px = h * 64 + nj * 32 + (l & 31);
    const int col = (q * 2 + lk) * 5;
    #pragma unroll
    for (int e = 0; e < 5; ++e) {
      simsL[px * 41 + col + e] = ts[nj][e];
      idsL[px * 41 + col + e] = ti[nj][e];
    }
  }
  __syncthreads();

  if (t < 128) {
    float m[8]; int n[8];
    #pragma unroll
    for (int j = 0; j < 8; ++j) { m[j] = -3.0e38f; n[j] = 0x7fffffff; }
    for (int c = 0; c < 40; ++c)
      ins8_(m, n, simsL[t * 41 + c], idsL[t * 41 + c]);
    const int gp = pb + t;
    #pragma unroll
    for (int j = 0; j < 8; ++j) ids8[(size_t)gp * 8 + j] = n[j];
  }
}

/* ------------- kernel 3b: exact f64 refinement of the 8 candidates ------------- */
__global__ __launch_bounds__(256) void refine_kernel(
    const float* __restrict__ feat, const float* __restrict__ lab,
    const int* __restrict__ ids8, float* __restrict__ out,
    int* __restrict__ cids) {
  const int t = threadIdx.x;
  const int lane = t & 63;
  const int p = blockIdx.x * 4 + (t >> 6);

  float4 f = *(const float4*)(feat + (size_t)p * EMB + lane * 4);
  const double fx = f.x, fy = f.y, fz = f.z, fw = f.w;
  double sf = fx * fx + fy * fy + fz * fz + fw * fw;

  int id[8];
  #pragma unroll
  for (int j = 0; j < 8; ++j) id[j] = ids8[(size_t)p * 8 + j];

  double dot[8], sl[8];
  #pragma unroll
  for (int j = 0; j < 8; ++j) {
    float4 lv = *(const float4*)(lab + (size_t)id[j] * EMB + lane * 4);
    const double lx = lv.x, ly = lv.y, lz = lv.z, lw = lv.w;
    dot[j] = fma(fx, lx, fma(fy, ly, fma(fz, lz, fw * lw)));
    sl[j]  = fma(lx, lx, fma(ly, ly, fma(lz, lz, lw * lw)));
  }
  #pragma unroll
  for (int off = 32; off >= 1; off >>= 1) {
    sf += __shfl_xor(sf, off);
    #pragma unroll
    for (int j = 0; j < 8; ++j) {
      dot[j] += __shfl_xor(dot[j], off);
      sl[j]  += __shfl_xor(sl[j], off);
    }
  }
  if (lane == 0) {
    const double invf = 1.0 / (sqrt(sf) + 1e-12);
    double s[8];
    #pragma unroll
    for (int j = 0; j < 8; ++j)
      s[j] = dot[j] * (1.0 / (sqrt(sl[j]) + 1e-12)) * invf;
    #pragma unroll
    for (int pass = 0; pass < 7; ++pass) {
      #pragma unroll
      for (int i = 0; i < 7; ++i) {
        if (i < 7 - pass) {
          if (betterd_(s[i + 1], id[i + 1], s[i], id[i])) {
            double tv = s[i]; s[i] = s[i + 1]; s[i + 1] = tv;
            int td = id[i]; id[i] = id[i + 1]; id[i + 1] = td;
          }
        }
      }
    }
    #pragma unroll
    for (int k = 0; k < 5; ++k) {
      out[OUT_CS + (size_t)p * 5 + k] = (float)s[k];
      cids[(size_t)p * 5 + k] = id[k];
    }
  }
}

/* ------------- kernel 4: abundance MLP (f32) + softmax + recon + dominant ------------- */
__global__ __launch_bounds__(256) void abund_kernel(
    const float* __restrict__ feat, const float* __restrict__ scores,
    const float* __restrict__ w1, const float* __restrict__ b1,
    const float* __restrict__ w2, const float* __restrict__ b2,
    const float* __restrict__ proto, const int* __restrict__ cids,
    float* __restrict__ out) {
  __shared__ __align__(16) float xs[16 * 264];
  __shared__ __align__(16) float hs[16 * 520];
  __shared__ float scs[16 * 5];
  __shared__ float lo[16 * 8];
  __shared__ float sAB[16 * 8];
  __shared__ int ids_s[16 * 5];
  const int t = threadIdx.x;
  const int pb = blockIdx.x * 16;

  #pragma unroll
  for (int i = 0; i < 4; ++i) {
    int F = i * 256 + t;
    int p = F >> 6, q = (F & 63) * 4;
    *(float4*)&xs[p * 264 + q] = *(const float4*)(feat + (size_t)(pb + p) * EMB + q);
  }
  if (t < 80) scs[t] = scores[(size_t)(pb + t / 5) * 5 + (t % 5)];
  __syncthreads();

  const int h0 = t, h1 = t + 256;
  float a0[16], a1[16];
  #pragma unroll
  for (int p = 0; p < 16; ++p) { a0[p] = 0.f; a1[p] = 0.f; }

  for (int i4 = 0; i4 < 64; ++i4) {
    const int i = i4 * 4;
    float w00 = w1[(i + 0) * HID + h0], w01 = w1[(i + 1) * HID + h0];
    float w02 = w1[(i + 2) * HID + h0], w03 = w1[(i + 3) * HID + h0];
    float w10 = w1[(i + 0) * HID + h1], w11 = w1[(i + 1) * HID + h1];
    float w12 = w1[(i + 2) * HID + h1], w13 = w1[(i + 3) * HID + h1];
    #pragma unroll
    for (int p = 0; p < 16; ++p) {
      float4 x = *(const float4*)&xs[p * 264 + i];
      a0[p] = fmaf(x.x, w00, a0[p]); a0[p] = fmaf(x.y, w01, a0[p]);
      a0[p] = fmaf(x.z, w02, a0[p]); a0[p] = fmaf(x.w, w03, a0[p]);
      a1[p] = fmaf(x.x, w10, a1[p]); a1[p] = fmaf(x.y, w11, a1[p]);
      a1[p] = fmaf(x.z, w12, a1[p]); a1[p] = fmaf(x.w, w13, a1[p]);
    }
  }
  #pragma unroll
  for (int r = 0; r < 5; ++r) {
    float wA = w1[(256 + r) * HID + h0], wB = w1[(256 + r) * HID + h1];
    #pragma unroll
    for (int p = 0; p < 16; ++p) {
      float x = scs[p * 5 + r];
      a0[p] = fmaf(x, wA, a0[p]);
      a1[p] = fmaf(x, wB, a1[p]);
    }
  }
  const float bb0 = b1[h0], bb1 = b1[h1];
  #pragma unroll
  for (int p = 0; p < 16; ++p) {
    hs[p * 520 + h0] = fmaxf(a0[p] + bb0, 0.f);
    hs[p * 520 + h1] = fmaxf(a1[p] + bb1, 0.f);
  }
  __syncthreads();

  if (t < 112) {
    const int p = t / 7, o = t % 7;
    float acc = b2[o];
    for (int h4 = 0; h4 < 128; ++h4) {
      float4 hv = *(const float4*)&hs[p * 520 + h4 * 4];
      acc = fmaf(hv.x, w2[(h4 * 4 + 0) * 7 + o], acc);
      acc = fmaf(hv.y, w2[(h4 * 4 + 1) * 7 + o], acc);
      acc = fmaf(hv.z, w2[(h4 * 4 + 2) * 7 + o], acc);
      acc = fmaf(hv.w, w2[(h4 * 4 + 3) * 7 + o], acc);
    }
    lo[p * 8 + o] = acc;
  }
  __syncthreads();

  if (t < 16) {
    const int p = t, gp = pb + t;
    float m = lo[p * 8 + 0];
    #pragma unroll
    for (int o = 1; o < 7; ++o) m = fmaxf(m, lo[p * 8 + o]);
    float e[7]; float ssum = 0.f;
    #pragma unroll
    for (int o = 0; o < 7; ++o) { e[o] = expf(lo[p * 8 + o] - m); ssum += e[o]; }
    const float inv = 1.0f / ssum;
    #pragma unroll
    for (int o = 0; o < 7; ++o) {
      float a = e[o] * inv;
      sAB[p * 8 + o] = a;
      out[OUT_AB + (size_t)gp * 7 + o] = a;
    }
    /* dominant: argmax over logits[:5] (softmax monotone) */
    int best = 0; float bv = lo[p * 8 + 0];
    #pragma unroll
    for (int k = 1; k < 5; ++k)
      if (lo[p * 8 + k] > bv) { bv = lo[p * 8 + k]; best = k; }
    #pragma unroll
    for (int k = 0; k < 5; ++k) ids_s[p * 5 + k] = cids[(size_t)gp * 5 + k];
    out[OUT_DOM + gp] = (float)ids_s[p * 5 + best];
  }
  __syncthreads();

  {
    const int p = t >> 4, l16 = t & 15;
    const int gp = pb + p, bz = l16 * 14;
    float r[14];
    #pragma unroll
    for (int j = 0; j < 14; ++j) r[j] = 0.f;
    #pragma unroll
    for (int k = 0; k < 5; ++k) {
      const int idk = ids_s[p * 5 + k];
      const float a = sAB[p * 8 + k];
      const float* pr = proto + (size_t)idk * NB + bz;
      #pragma unroll
      for (int j = 0; j < 14; ++j) r[j] = fmaf(a, pr[j], r[j]);
    }
    #pragma unroll
    for (int j = 0; j < 14; ++j) out[OUT_RE + (size_t)gp * NB + bz + j] = r[j];
  }
}

extern "C" void kernel_launch(void* const* d_in, const int* in_sizes, int n_in,
                              void* d_out, int out_size, void* d_ws, size_t ws_size,
                              hipStream_t stream) {
  (void)in_sizes; (void)n_in; (void)out_size; (void)ws_size;
  const float* feat  = (const float*)d_in[0];
  const float* w1_s  = (const float*)d_in[1];
  const float* b1_s  = (const float*)d_in[2];
  const float* w2_s  = (const float*)d_in[3];
  const float* b2_s  = (const float*)d_in[4];
  const float* w1_a  = (const float*)d_in[5];
  const float* b1_a  = (const float*)d_in[6];
  const float* w2_a  = (const float*)d_in[7];
  const float* b2_a  = (const float*)d_in[8];
  const float* lab   = (const float*)d_in[9];
  const float* proto = (const float*)d_in[10];
  float* out = (float*)d_out;
  char* ws = (char*)d_ws;
  float* wscores = (float*)(ws + WS_SCORES);
  float* winvl   = (float*)(ws + WS_INVL);
  int*   wids8   = (int*)(ws + WS_IDS8);
  int*   wcids   = (int*)(ws + WS_CIDS);
  char*  wlab    = ws + WS_LAB;

  (void)hipFuncSetAttribute(reinterpret_cast<const void*>(sims_topk_kernel),
                            hipFuncAttributeMaxDynamicSharedMemorySize, 131072);

  labsplit_kernel<<<dim3(NLIB), dim3(64), 0, stream>>>(lab, wlab);
  libnorm_kernel<<<dim3(NLIB), dim3(64), 0, stream>>>(lab, winvl);
  score_mlp_kernel<<<dim3(P_TOT / 16), dim3(256), 0, stream>>>(
      feat, w1_s, b1_s, w2_s, b2_s, wscores);
  sims_topk_kernel<<<dim3(P_TOT / 128), dim3(512), 131072, stream>>>(
      feat, wlab, winvl, wids8);
  refine_kernel<<<dim3(P_TOT / 4), dim3(256), 0, stream>>>(
      feat, lab, wids8, out, wcids);
  abund_kernel<<<dim3(P_TOT / 16), dim3(256), 0, stream>>>(
      feat, wscores, w1_a, b1_a, w2_a, b2_a, proto, wcids, out);
}